// Round 4
// baseline (6630.070 us; speedup 1.0000x reference)
//
#include <hip/hip_runtime.h>

#define N_PTS 200000
#define KC    512
#define DIM   128
#define NITER 3
#define EPS   1e-10
#define BETA  1e-3

// ---------------- k_init: C_T (f64 transposed), csq, zero num/den ----------------
__global__ void k_init(const float* __restrict__ cin, double* __restrict__ C_T,
                       double* __restrict__ csq, double* __restrict__ num,
                       double* __restrict__ den) {
    int k = blockIdx.x, d = threadIdx.x;      // 512 blocks x 128 threads
    double c = (double)cin[k * DIM + d];
    C_T[(size_t)d * KC + k] = c;
    num[(size_t)k * DIM + d] = 0.0;
    double p = c * c;
    #pragma unroll
    for (int m = 1; m < 64; m <<= 1) p += __shfl_xor(p, m);
    __shared__ double ps[2];
    if ((d & 63) == 0) ps[d >> 6] = p;
    __syncthreads();
    if (d == 0) { csq[k] = ps[0] + ps[1]; den[k] = 0.0; }
}

// ---------------- k_dense: full f64 dist + softmax + atomic scatter ----------------
// 256 threads = 4 waves; 8 points/block (2/wave); centers in 8 chunks of 64.
// Lane l owns center ch*64+l. Faithful op order: ((x_sq - 2P) + c_sq), z=-d/beta,
// arg=z-zmax, exp, sum; args < -745 are exactly-zero weights in f64 (skipped).
__launch_bounds__(256)
__global__ void k_dense(const float* __restrict__ x, const double* __restrict__ C_T,
                        const double* __restrict__ csq, double* __restrict__ num,
                        double* __restrict__ den) {
    __shared__ double xs[8 * DIM];            // 8 KB
    __shared__ double cs[DIM * 64];           // 64 KB, cs[d*64 + cl]
    __shared__ double csqs[KC];               // 4 KB

    const int tid = threadIdx.x;
    const int pbase = blockIdx.x * 8;         // 25000 blocks * 8 = 200000 exactly

    #pragma unroll
    for (int s = 0; s < 4; ++s) {
        int f = tid + s * 256;                // [0,1024)
        int p = f >> 7, d = f & 127;
        xs[f] = (double)x[(size_t)(pbase + p) * DIM + d];
    }
    csqs[tid] = csq[tid];
    csqs[tid + 256] = csq[tid + 256];
    __syncthreads();

    const int wv = tid >> 6, lane = tid & 63;

    // ||x||^2 per point (common-mode in softmax; kept for faithfulness)
    double xsq[2];
    #pragma unroll
    for (int q = 0; q < 2; ++q) {
        int p = wv * 2 + q;
        double a = xs[p * DIM + lane], b = xs[p * DIM + 64 + lane];
        double ss = a * a + b * b;
        #pragma unroll
        for (int m = 1; m < 64; m <<= 1) ss += __shfl_xor(ss, m);
        xsq[q] = ss;
    }

    double dd[2][8];
    for (int ch = 0; ch < 8; ++ch) {
        __syncthreads();
        #pragma unroll
        for (int s = 0; s < 32; ++s) {
            int f = tid + s * 256;            // [0,8192)
            int d = f >> 6, cl = f & 63;
            cs[f] = C_T[(size_t)d * KC + ch * 64 + cl];
        }
        __syncthreads();
        double acc0 = 0.0, acc1 = 0.0;
        #pragma unroll 4
        for (int d = 0; d < DIM; ++d) {
            double cv = cs[d * 64 + lane];
            acc0 += xs[(wv * 2 + 0) * DIM + d] * cv;   // wave-uniform broadcast
            acc1 += xs[(wv * 2 + 1) * DIM + d] * cv;
        }
        double cq = csqs[ch * 64 + lane];
        dd[0][ch] = (xsq[0] - 2.0 * acc0) + cq;
        dd[1][ch] = (xsq[1] - 2.0 * acc1) + cq;
    }

    #pragma unroll
    for (int q = 0; q < 2; ++q) {
        int p = wv * 2 + q;
        double md = dd[q][0];
        #pragma unroll
        for (int j = 1; j < 8; ++j) md = fmin(md, dd[q][j]);
        #pragma unroll
        for (int m = 1; m < 64; m <<= 1) md = fmin(md, __shfl_xor(md, m));
        double zm = -md / BETA;               // = max_k z_k (fl monotone)
        double argv[8];
        double esum = 0.0;
        #pragma unroll
        for (int j = 0; j < 8; ++j) {
            double z = -dd[q][j] / BETA;
            double a = z - zm;
            argv[j] = a;
            if (a >= -745.0) esum += exp(a);
        }
        #pragma unroll
        for (int m = 1; m < 64; m <<= 1) esum += __shfl_xor(esum, m);

        // scatter nonzero weights; whole wave cooperates per candidate
        #pragma unroll
        for (int j = 0; j < 8; ++j) {
            unsigned long long msk = __ballot(argv[j] >= -745.0);
            while (msk) {
                int l = __ffsll(msk) - 1;
                msk &= msk - 1;
                double aw = __shfl(argv[j], l);
                double wgt = exp(aw) / esum;
                int k = j * 64 + l;
                atomicAdd(&num[(size_t)k * DIM + lane],      wgt * xs[p * DIM + lane]);
                atomicAdd(&num[(size_t)k * DIM + 64 + lane], wgt * xs[p * DIM + 64 + lane]);
                if (lane == 0) atomicAdd(&den[k], wgt);
            }
        }
    }
}

// ---------------- k_update: centers = num/(den+EPS); refresh C_T/csq; zero num/den ----------------
__global__ void k_update(double* __restrict__ num, double* __restrict__ den,
                         double* __restrict__ C_T, double* __restrict__ csq,
                         float* __restrict__ out, int last) {
    int k = blockIdx.x, d = threadIdx.x;      // 512 blocks x 128 threads
    double nv = num[(size_t)k * DIM + d];
    double dv = den[k] + EPS;
    double c = nv / dv;
    C_T[(size_t)d * KC + k] = c;
    num[(size_t)k * DIM + d] = 0.0;
    if (last) out[k * DIM + d] = (float)c;
    double p = c * c;
    #pragma unroll
    for (int m = 1; m < 64; m <<= 1) p += __shfl_xor(p, m);
    __shared__ double ps[2];
    if ((d & 63) == 0) ps[d >> 6] = p;
    __syncthreads();
    if (d == 0) { csq[k] = ps[0] + ps[1]; den[k] = 0.0; }
}

extern "C" void kernel_launch(void* const* d_in, const int* in_sizes, int n_in,
                              void* d_out, int out_size, void* d_ws, size_t ws_size,
                              hipStream_t stream) {
    const float* x   = (const float*)d_in[0];
    const float* cin = (const float*)d_in[1];
    float* out = (float*)d_out;

    char* w = (char*)d_ws;
    size_t off = 0;
    auto alloc = [&](size_t bytes) -> void* {
        void* p = w + off;
        off = (off + bytes + 255) & ~(size_t)255;
        return p;
    };
    double* C_T = (double*)alloc((size_t)DIM * KC * 8);   // 512 KB
    double* csq = (double*)alloc((size_t)KC * 8);
    double* num = (double*)alloc((size_t)KC * DIM * 8);   // 512 KB
    double* den = (double*)alloc((size_t)KC * 8);
    (void)ws_size; (void)in_sizes; (void)n_in; (void)out_size;

    hipLaunchKernelGGL(k_init, dim3(KC), dim3(DIM), 0, stream, cin, C_T, csq, num, den);

    for (int it = 0; it < NITER; ++it) {
        hipLaunchKernelGGL(k_dense, dim3(N_PTS / 8), dim3(256), 0, stream,
                           x, C_T, csq, num, den);
        hipLaunchKernelGGL(k_update, dim3(KC), dim3(DIM), 0, stream,
                           num, den, C_T, csq, out, (it == NITER - 1) ? 1 : 0);
    }
}

// Round 5
// 4734.126 us; speedup vs baseline: 1.4005x; 1.4005x over previous
//
#include <hip/hip_runtime.h>

#define N_PTS 200000
#define KC    512
#define DIM   128
#define NITER 3
#define EPS   1e-10
#define BETA  1e-3

// ---------------- k_init: C_T (f64 transposed), csq, zero num/den ----------------
__global__ void k_init(const float* __restrict__ cin, double* __restrict__ C_T,
                       double* __restrict__ csq, double* __restrict__ num,
                       double* __restrict__ den) {
    int k = blockIdx.x, d = threadIdx.x;      // 512 blocks x 128 threads
    double c = (double)cin[k * DIM + d];
    C_T[(size_t)d * KC + k] = c;
    num[(size_t)k * DIM + d] = 0.0;
    double p = c * c;
    #pragma unroll
    for (int m = 1; m < 64; m <<= 1) p += __shfl_xor(p, m);
    __shared__ double ps[2];
    if ((d & 63) == 0) ps[d >> 6] = p;
    __syncthreads();
    if (d == 0) { csq[k] = ps[0] + ps[1]; den[k] = 0.0; }
}

// ---------------- k_dense: full f64 dist + softmax + atomic scatter ----------------
// 256 threads = 4 waves; 16 points/block (4/wave); centers in 8 chunks of 64.
// Lane l owns center ch*64+l. 4 independent FMA chains/lane; x-broadcasts via b128.
__launch_bounds__(256)
__global__ void k_dense(const float* __restrict__ x, const double* __restrict__ C_T,
                        const double* __restrict__ csq, double* __restrict__ num,
                        double* __restrict__ den) {
    __shared__ double xs[16 * DIM];           // 16 KB
    __shared__ double cs[DIM * 64];           // 64 KB, cs[d*64 + cl]

    const int tid = threadIdx.x;
    const int pbase = blockIdx.x * 16;        // 12500 blocks * 16 = 200000 exactly

    // stage x (f32 global -> f64 LDS), coalesced reads, conflict-free writes
    #pragma unroll
    for (int s = 0; s < 8; ++s) {
        int f = tid + s * 256;                // [0,2048)
        int p = f >> 7, d = f & 127;
        xs[f] = (double)x[(size_t)(pbase + p) * DIM + d];
    }
    __syncthreads();

    const int wv = tid >> 6, lane = tid & 63;
    const int p0 = wv * 4;

    // ||x||^2 per point (common-mode; kept for faithfulness)
    double xsq[4];
    #pragma unroll
    for (int q = 0; q < 4; ++q) {
        double a = xs[(p0 + q) * DIM + lane], b = xs[(p0 + q) * DIM + 64 + lane];
        double ss = a * a + b * b;
        #pragma unroll
        for (int m = 1; m < 64; m <<= 1) ss += __shfl_xor(ss, m);
        xsq[q] = ss;
    }

    double dd[4][8];
    const double2* xs2 = (const double2*)xs;

    #pragma unroll
    for (int ch = 0; ch < 8; ++ch) {
        __syncthreads();
        #pragma unroll
        for (int s = 0; s < 32; ++s) {
            int f = tid + s * 256;            // [0,8192)
            int d = f >> 6, cl = f & 63;
            cs[f] = C_T[(size_t)d * KC + ch * 64 + cl];
        }
        __syncthreads();

        double a0 = 0.0, a1 = 0.0, a2 = 0.0, a3 = 0.0;
        #pragma unroll 4
        for (int d = 0; d < DIM; d += 2) {
            double c0 = cs[d * 64 + lane];
            double c1 = cs[(d + 1) * 64 + lane];
            double2 x0 = xs2[((p0 + 0) * DIM + d) >> 1];  // wave-uniform broadcast
            double2 x1 = xs2[((p0 + 1) * DIM + d) >> 1];
            double2 x2 = xs2[((p0 + 2) * DIM + d) >> 1];
            double2 x3 = xs2[((p0 + 3) * DIM + d) >> 1];
            a0 += x0.x * c0; a0 += x0.y * c1;
            a1 += x1.x * c0; a1 += x1.y * c1;
            a2 += x2.x * c0; a2 += x2.y * c1;
            a3 += x3.x * c0; a3 += x3.y * c1;
        }
        double cq = csq[ch * 64 + lane];      // L2-hit global read (LDS budget)
        dd[0][ch] = (xsq[0] - 2.0 * a0) + cq;
        dd[1][ch] = (xsq[1] - 2.0 * a1) + cq;
        dd[2][ch] = (xsq[2] - 2.0 * a2) + cq;
        dd[3][ch] = (xsq[3] - 2.0 * a3) + cq;
    }

    #pragma unroll
    for (int q = 0; q < 4; ++q) {
        int p = p0 + q;
        double md = dd[q][0];
        #pragma unroll
        for (int j = 1; j < 8; ++j) md = fmin(md, dd[q][j]);
        #pragma unroll
        for (int m = 1; m < 64; m <<= 1) md = fmin(md, __shfl_xor(md, m));
        double zm = -md / BETA;               // = max_k z_k (fl monotone)
        double argv[8];
        double esum = 0.0;
        #pragma unroll
        for (int j = 0; j < 8; ++j) {
            double z = -dd[q][j] / BETA;
            double a = z - zm;
            argv[j] = a;
            if (a >= -745.0) esum += exp(a);
        }
        #pragma unroll
        for (int m = 1; m < 64; m <<= 1) esum += __shfl_xor(esum, m);

        // scatter nonzero weights; whole wave cooperates per candidate
        #pragma unroll
        for (int j = 0; j < 8; ++j) {
            unsigned long long msk = __ballot(argv[j] >= -745.0);
            while (msk) {
                int l = __ffsll(msk) - 1;
                msk &= msk - 1;
                double aw = __shfl(argv[j], l);
                double wgt = exp(aw) / esum;
                int k = j * 64 + l;
                atomicAdd(&num[(size_t)k * DIM + lane],      wgt * xs[p * DIM + lane]);
                atomicAdd(&num[(size_t)k * DIM + 64 + lane], wgt * xs[p * DIM + 64 + lane]);
                if (lane == 0) atomicAdd(&den[k], wgt);
            }
        }
    }
}

// ---------------- k_update: centers = num/(den+EPS); refresh C_T/csq; zero num/den ----------------
__global__ void k_update(double* __restrict__ num, double* __restrict__ den,
                         double* __restrict__ C_T, double* __restrict__ csq,
                         float* __restrict__ out, int last) {
    int k = blockIdx.x, d = threadIdx.x;      // 512 blocks x 128 threads
    double nv = num[(size_t)k * DIM + d];
    double dv = den[k] + EPS;
    double c = nv / dv;
    C_T[(size_t)d * KC + k] = c;
    num[(size_t)k * DIM + d] = 0.0;
    if (last) out[k * DIM + d] = (float)c;
    double p = c * c;
    #pragma unroll
    for (int m = 1; m < 64; m <<= 1) p += __shfl_xor(p, m);
    __shared__ double ps[2];
    if ((d & 63) == 0) ps[d >> 6] = p;
    __syncthreads();
    if (d == 0) { csq[k] = ps[0] + ps[1]; den[k] = 0.0; }
}

extern "C" void kernel_launch(void* const* d_in, const int* in_sizes, int n_in,
                              void* d_out, int out_size, void* d_ws, size_t ws_size,
                              hipStream_t stream) {
    const float* x   = (const float*)d_in[0];
    const float* cin = (const float*)d_in[1];
    float* out = (float*)d_out;

    char* w = (char*)d_ws;
    size_t off = 0;
    auto alloc = [&](size_t bytes) -> void* {
        void* p = w + off;
        off = (off + bytes + 255) & ~(size_t)255;
        return p;
    };
    double* C_T = (double*)alloc((size_t)DIM * KC * 8);   // 512 KB
    double* csq = (double*)alloc((size_t)KC * 8);
    double* num = (double*)alloc((size_t)KC * DIM * 8);   // 512 KB
    double* den = (double*)alloc((size_t)KC * 8);
    (void)ws_size; (void)in_sizes; (void)n_in; (void)out_size;

    hipLaunchKernelGGL(k_init, dim3(KC), dim3(DIM), 0, stream, cin, C_T, csq, num, den);

    for (int it = 0; it < NITER; ++it) {
        hipLaunchKernelGGL(k_dense, dim3(N_PTS / 16), dim3(256), 0, stream,
                           x, C_T, csq, num, den);
        hipLaunchKernelGGL(k_update, dim3(KC), dim3(DIM), 0, stream,
                           num, den, C_T, csq, out, (it == NITER - 1) ? 1 : 0);
    }
}

// Round 6
// 2312.417 us; speedup vs baseline: 2.8672x; 2.0473x over previous
//
#include <hip/hip_runtime.h>

#define N_PTS 200000
#define KC    512
#define DIM   128
#define NITER 3
#define EPS   1e-10
#define BETA  1e-3
#define PWIN  0.0335f   // pruner window: f64 arg>=-32 band (0.032) + f32-dot slack
#define ACUT  -32.0     // weights below e^-32 shift centers ~1e-12 -> ~4e-9 final

// ---------------- k_init: Cf64 row-major, CT32 transposed f32, csq, zero num/den ----------------
__global__ void k_init(const float* __restrict__ cin, double* __restrict__ Cf64,
                       float* __restrict__ CT32, double* __restrict__ csqd,
                       float* __restrict__ csqf, double* __restrict__ num,
                       double* __restrict__ den) {
    int k = blockIdx.x, d = threadIdx.x;      // 512 blocks x 128 threads
    float v = cin[k * DIM + d];
    double c = (double)v;
    Cf64[(size_t)k * DIM + d] = c;
    CT32[d * KC + k] = v;
    num[(size_t)k * DIM + d] = 0.0;
    double p = c * c;
    #pragma unroll
    for (int m = 1; m < 64; m <<= 1) p += __shfl_xor(p, m);
    __shared__ double ps[2];
    if ((d & 63) == 0) ps[d >> 6] = p;
    __syncthreads();
    if (d == 0) { double s = ps[0] + ps[1]; csqd[k] = s; csqf[k] = (float)s; den[k] = 0.0; }
}

// ---------------- k_dense: f32 pruner GEMM + exact f64 refine + atomic scatter ----------------
// 256 threads = 4 waves; 16 points/block (4/wave); centers in 8 chunks of 64.
// Lane l owns center ch*64+l in the pruner. Refine is wave-cooperative per candidate.
__launch_bounds__(256, 4)
__global__ void k_dense(const float* __restrict__ x, const float* __restrict__ CT32,
                        const float* __restrict__ csqf, const double* __restrict__ Cf64,
                        const double* __restrict__ csqd,
                        double* __restrict__ num, double* __restrict__ den) {
    __shared__ float  xsf[16 * DIM];          // 8 KB
    __shared__ float2 cs2[64 * 64];           // 32 KB: cs2[d2*64+cl] = C[ch*64+cl][2d2,2d2+1]

    const int tid = threadIdx.x;
    const int pbase = blockIdx.x * 16;        // 12500 * 16 = 200000 exactly

    #pragma unroll
    for (int s = 0; s < 8; ++s) {
        int f = tid + s * 256;                // [0,2048)
        xsf[f] = x[(size_t)pbase * DIM + f];  // fully coalesced
    }

    const int wv = tid >> 6, lane = tid & 63;
    const int p0 = wv * 4;
    const float4* xs4 = (const float4*)xsf;

    float dd[4][8];
    #pragma unroll
    for (int ch = 0; ch < 8; ++ch) {
        __syncthreads();
        #pragma unroll
        for (int s = 0; s < 16; ++s) {
            int f = tid + s * 256;            // [0,4096)
            int d2 = f >> 6, cl = f & 63;
            float lo = CT32[(2 * d2) * KC + ch * 64 + cl];
            float hi = CT32[(2 * d2 + 1) * KC + ch * 64 + cl];
            cs2[f] = make_float2(lo, hi);
        }
        __syncthreads();

        float a0 = 0.f, a1 = 0.f, a2 = 0.f, a3 = 0.f;
        #pragma unroll 8
        for (int d4 = 0; d4 < 32; ++d4) {
            float2 cA = cs2[(2 * d4) * 64 + lane];       // dims 4d4,4d4+1
            float2 cB = cs2[(2 * d4 + 1) * 64 + lane];   // dims 4d4+2,4d4+3
            float4 x0 = xs4[(p0 + 0) * 32 + d4];         // wave-uniform broadcast
            float4 x1 = xs4[(p0 + 1) * 32 + d4];
            float4 x2 = xs4[(p0 + 2) * 32 + d4];
            float4 x3 = xs4[(p0 + 3) * 32 + d4];
            a0 += x0.x * cA.x; a0 += x0.y * cA.y; a0 += x0.z * cB.x; a0 += x0.w * cB.y;
            a1 += x1.x * cA.x; a1 += x1.y * cA.y; a1 += x1.z * cB.x; a1 += x1.w * cB.y;
            a2 += x2.x * cA.x; a2 += x2.y * cA.y; a2 += x2.z * cB.x; a2 += x2.w * cB.y;
            a3 += x3.x * cA.x; a3 += x3.y * cA.y; a3 += x3.z * cB.x; a3 += x3.w * cB.y;
        }
        float cq = csqf[ch * 64 + lane];      // L2-hit broadcast row
        dd[0][ch] = cq - 2.f * a0;            // xsq omitted: common mode, pruner only
        dd[1][ch] = cq - 2.f * a1;
        dd[2][ch] = cq - 2.f * a2;
        dd[3][ch] = cq - 2.f * a3;
    }

    #pragma unroll
    for (int q = 0; q < 4; ++q) {
        int p = p0 + q;
        // exact f64 ||x||^2 (faithful op order for dist)
        double xa = (double)xsf[p * DIM + lane];
        double xb = (double)xsf[p * DIM + 64 + lane];
        double ss = xa * xa + xb * xb;
        #pragma unroll
        for (int m = 1; m < 64; m <<= 1) ss += __shfl_xor(ss, m);

        // global f32 min over all 512 (full min BEFORE candidate collection)
        float mf = dd[q][0];
        #pragma unroll
        for (int j = 1; j < 8; ++j) mf = fminf(mf, dd[q][j]);
        #pragma unroll
        for (int m = 1; m < 64; m <<= 1) mf = fminf(mf, __shfl_xor(mf, m));

        // collect candidates; lane c holds candidate c's exact f64 dist
        double myd = 1e300;
        int myk = -1;
        int c = 0;
        for (int j = 0; j < 8; ++j) {
            unsigned long long msk = __ballot(dd[q][j] - mf < PWIN);
            while (msk) {
                int l = __ffsll(msk) - 1;
                msk &= msk - 1;
                int k = j * 64 + l;
                double ca = Cf64[(size_t)k * DIM + lane];
                double cb = Cf64[(size_t)k * DIM + 64 + lane];
                double pr = xa * ca + xb * cb;
                #pragma unroll
                for (int m = 1; m < 64; m <<= 1) pr += __shfl_xor(pr, m);
                double dist = (ss - 2.0 * pr) + csqd[k];
                if (lane == c) { myd = dist; myk = k; }
                ++c;
            }
        }

        // exact f64 softmax over candidate lanes
        double md = myd;
        #pragma unroll
        for (int m = 1; m < 64; m <<= 1) md = fmin(md, __shfl_xor(md, m));
        double zm = -md / BETA;
        double arg = (myk >= 0) ? (-myd / BETA - zm) : -1e300;
        double e = (myk >= 0) ? exp(arg) : 0.0;
        double esum = e;
        #pragma unroll
        for (int m = 1; m < 64; m <<= 1) esum += __shfl_xor(esum, m);

        // scatter candidates with arg >= ACUT (wave-cooperative, 128 dims over 2x64 lanes)
        unsigned long long smsk = __ballot(myk >= 0 && arg >= ACUT);
        while (smsk) {
            int l = __ffsll(smsk) - 1;
            smsk &= smsk - 1;
            double aw = __shfl(arg, l);
            int k = __shfl(myk, l);
            double wgt = exp(aw) / esum;
            atomicAdd(&num[(size_t)k * DIM + lane],      wgt * xa);
            atomicAdd(&num[(size_t)k * DIM + 64 + lane], wgt * xb);
            if (lane == 0) atomicAdd(&den[k], wgt);
        }
    }
}

// ---------------- k_update: centers = num/(den+EPS); refresh Cf64/CT32/csq; zero ----------------
__global__ void k_update(double* __restrict__ num, double* __restrict__ den,
                         double* __restrict__ Cf64, float* __restrict__ CT32,
                         double* __restrict__ csqd, float* __restrict__ csqf,
                         float* __restrict__ out, int last) {
    int k = blockIdx.x, d = threadIdx.x;      // 512 blocks x 128 threads
    double nv = num[(size_t)k * DIM + d];
    double dv = den[k] + EPS;
    double c = nv / dv;
    Cf64[(size_t)k * DIM + d] = c;
    CT32[d * KC + k] = (float)c;
    num[(size_t)k * DIM + d] = 0.0;
    if (last) out[k * DIM + d] = (float)c;
    double p = c * c;
    #pragma unroll
    for (int m = 1; m < 64; m <<= 1) p += __shfl_xor(p, m);
    __shared__ double ps[2];
    if ((d & 63) == 0) ps[d >> 6] = p;
    __syncthreads();
    if (d == 0) { double s = ps[0] + ps[1]; csqd[k] = s; csqf[k] = (float)s; den[k] = 0.0; }
}

extern "C" void kernel_launch(void* const* d_in, const int* in_sizes, int n_in,
                              void* d_out, int out_size, void* d_ws, size_t ws_size,
                              hipStream_t stream) {
    const float* x   = (const float*)d_in[0];
    const float* cin = (const float*)d_in[1];
    float* out = (float*)d_out;

    char* w = (char*)d_ws;
    size_t off = 0;
    auto alloc = [&](size_t bytes) -> void* {
        void* p = w + off;
        off = (off + bytes + 255) & ~(size_t)255;
        return p;
    };
    double* Cf64 = (double*)alloc((size_t)KC * DIM * 8);  // 512 KB
    float*  CT32 = (float*)alloc((size_t)DIM * KC * 4);   // 256 KB
    double* csqd = (double*)alloc((size_t)KC * 8);
    float*  csqf = (float*)alloc((size_t)KC * 4);
    double* num  = (double*)alloc((size_t)KC * DIM * 8);  // 512 KB
    double* den  = (double*)alloc((size_t)KC * 8);
    (void)ws_size; (void)in_sizes; (void)n_in; (void)out_size;

    hipLaunchKernelGGL(k_init, dim3(KC), dim3(DIM), 0, stream,
                       cin, Cf64, CT32, csqd, csqf, num, den);

    for (int it = 0; it < NITER; ++it) {
        hipLaunchKernelGGL(k_dense, dim3(N_PTS / 16), dim3(256), 0, stream,
                           x, CT32, csqf, Cf64, csqd, num, den);
        hipLaunchKernelGGL(k_update, dim3(KC), dim3(DIM), 0, stream,
                           num, den, Cf64, CT32, csqd, csqf, out,
                           (it == NITER - 1) ? 1 : 0);
    }
}

// Round 7
// 878.158 us; speedup vs baseline: 7.5500x; 2.6333x over previous
//
#include <hip/hip_runtime.h>

#define N_PTS 200000
#define KC    512
#define DIM   128
#define NITER 3
#define EPS   1e-10
#define BETA  1e-3
#define PWIN  0.35f     // bf16-pruner window: f64 arg>=-32 band (0.032) + >10sigma bf16 slack
#define ACUT  -32.0     // weights below e^-32 shift centers ~1e-12 -> negligible
#define LCAND 16

typedef __attribute__((ext_vector_type(8)))  short short8;   // 8 bf16 (4 VGPR) MFMA A/B frag
typedef __attribute__((ext_vector_type(16))) float f32x16;   // 32x32 MFMA accumulator

__device__ inline unsigned short f2bf(float f) {             // f32 -> bf16 RNE
    unsigned u = __float_as_uint(f);
    unsigned r = u + 0x7FFFu + ((u >> 16) & 1u);
    return (unsigned short)(r >> 16);
}

// A/B fragment layout for mfma_f32_32x32x16_bf16: entity row/col = lane&31,
// k = (lane>>5)*8 + i, i=0..7. Packed flat: [(tile*8 + kb)*64 + lane] as short8.

// ---------------- k_packx: X -> bf16 A-fragments (once; x is iteration-invariant) ----------------
__global__ void k_packx(const float* __restrict__ x, short8* __restrict__ Xf) {
    int pt = blockIdx.x;                       // 6250 point-tiles of 32
    int tid = threadIdx.x;                     // 256
    int lane = tid & 63, g = tid >> 6;
    int row = pt * 32 + (lane & 31);
    int koff = (lane >> 5) * 8;
    #pragma unroll
    for (int kk = 0; kk < 2; ++kk) {
        int kb = g * 2 + kk;
        short8 v;
        #pragma unroll
        for (int i = 0; i < 8; ++i)
            ((unsigned short*)&v)[i] = f2bf(x[(size_t)row * DIM + kb * 16 + koff + i]);
        Xf[((size_t)pt * 8 + kb) * 64 + lane] = v;
    }
}

// ---------------- k_init: Cf64, C-fragments, csq, zero num/den ----------------
__global__ void k_init(const float* __restrict__ cin, double* __restrict__ Cf64,
                       unsigned short* __restrict__ Cfrag, double* __restrict__ csqd,
                       float* __restrict__ csqf, double* __restrict__ num,
                       double* __restrict__ den) {
    int k = blockIdx.x, d = threadIdx.x;       // 512 blocks x 128 threads
    float v = cin[k * DIM + d];
    double c = (double)v;
    Cf64[(size_t)k * DIM + d] = c;
    num[(size_t)k * DIM + d] = 0.0;
    int ct = k >> 5, kb = d >> 4, j = d & 15;
    int lane = (k & 31) + 32 * (j >> 3);
    Cfrag[(((size_t)ct * 8 + kb) * 64 + lane) * 8 + (j & 7)] = f2bf(v);
    double p = c * c;
    #pragma unroll
    for (int m = 1; m < 64; m <<= 1) p += __shfl_xor(p, m);
    __shared__ double ps[2];
    if ((d & 63) == 0) ps[d >> 6] = p;
    __syncthreads();
    if (d == 0) { double s = ps[0] + ps[1]; csqd[k] = s; csqf[k] = (float)s; den[k] = 0.0; }
}

// ---------------- k_dense: MFMA bf16 pruner + full-min + f64 refine + scatter ----------------
// 256 threads = 4 waves; 32 points/block; wave wv covers col-tiles wv*4..wv*4+3 (128 centers).
__launch_bounds__(256)
__global__ void k_dense(const float* __restrict__ x, const short8* __restrict__ Xf,
                        const short8* __restrict__ Cfrag, const float* __restrict__ csqf,
                        const double* __restrict__ Cf64, const double* __restrict__ csqd,
                        double* __restrict__ num, double* __restrict__ den) {
    __shared__ float rowmin_w[4][32];
    __shared__ float rowmin_s[32];
    __shared__ int   ccnt[32];
    __shared__ unsigned short clist[32][LCAND];

    const int tid = threadIdx.x;
    const int wv = tid >> 6, lane = tid & 63;
    const int blk = blockIdx.x;                // 6250 * 32 = 200000 exactly

    // A-fragments: this block's 32 points, full K=128 (32 VGPR)
    short8 a[8];
    #pragma unroll
    for (int kb = 0; kb < 8; ++kb)
        a[kb] = Xf[((size_t)blk * 8 + kb) * 64 + lane];

    // pruner: dd[t][r] = csq - 2*(x.c) in bf16/f32, held in registers
    float dd[4][16];
    #pragma unroll
    for (int t = 0; t < 4; ++t) {
        int ct = wv * 4 + t;
        f32x16 acc;
        #pragma unroll
        for (int r = 0; r < 16; ++r) acc[r] = 0.0f;
        #pragma unroll
        for (int kb = 0; kb < 8; ++kb) {
            short8 b = Cfrag[((size_t)ct * 8 + kb) * 64 + lane];
            acc = __builtin_amdgcn_mfma_f32_32x32x16_bf16(a[kb], b, acc, 0, 0, 0);
        }
        float cq = csqf[ct * 32 + (lane & 31)];
        #pragma unroll
        for (int r = 0; r < 16; ++r) dd[t][r] = cq - 2.0f * acc[r];
    }

    // per-row min over this wave's 128 cols (C/D layout: col=lane&31, row=(r&3)+8*(r>>2)+4*(lane>>5))
    float mt[16];
    #pragma unroll
    for (int r = 0; r < 16; ++r) {
        float m = fminf(fminf(dd[0][r], dd[1][r]), fminf(dd[2][r], dd[3][r]));
        #pragma unroll
        for (int s = 16; s >= 1; s >>= 1) m = fminf(m, __shfl_xor(m, s));
        mt[r] = m;
    }
    if ((lane & 31) == 0) {
        int h = lane >> 5;
        #pragma unroll
        for (int r = 0; r < 16; ++r)
            rowmin_w[wv][(r & 3) + 8 * (r >> 2) + 4 * h] = mt[r];
    }
    __syncthreads();
    if (tid < 32) {
        rowmin_s[tid] = fminf(fminf(rowmin_w[0][tid], rowmin_w[1][tid]),
                              fminf(rowmin_w[2][tid], rowmin_w[3][tid]));
        ccnt[tid] = 0;
    }
    __syncthreads();

    // candidate collection (full global min known BEFORE any collection)
    {
        const int h = lane >> 5;
        #pragma unroll
        for (int t = 0; t < 4; ++t) {
            int ct = wv * 4 + t;
            #pragma unroll
            for (int r = 0; r < 16; ++r) {
                int row = (r & 3) + 8 * (r >> 2) + 4 * h;
                if (dd[t][r] - rowmin_s[row] < PWIN) {
                    int idx = atomicAdd(&ccnt[row], 1);
                    if (idx < LCAND)
                        clist[row][idx] = (unsigned short)(ct * 32 + (lane & 31));
                }
            }
        }
    }
    __syncthreads();

    // exact f64 refine + softmax + scatter; wave wv handles points wv*8..wv*8+7
    for (int q = 0; q < 8; ++q) {
        int p = wv * 8 + q;
        int n = blk * 32 + p;
        int cnt = ccnt[p]; if (cnt > LCAND) cnt = LCAND;
        double xa = (double)x[(size_t)n * DIM + lane];
        double xb = (double)x[(size_t)n * DIM + 64 + lane];
        double ss = xa * xa + xb * xb;
        #pragma unroll
        for (int m = 1; m < 64; m <<= 1) ss += __shfl_xor(ss, m);

        double myd = 1e300; int myk = -1;
        for (int c = 0; c < cnt; ++c) {
            int k = clist[p][c];
            double pr = xa * Cf64[(size_t)k * DIM + lane] + xb * Cf64[(size_t)k * DIM + 64 + lane];
            #pragma unroll
            for (int m = 1; m < 64; m <<= 1) pr += __shfl_xor(pr, m);
            double dist = (ss - 2.0 * pr) + csqd[k];
            if (lane == c) { myd = dist; myk = k; }
        }
        double md = myd;
        #pragma unroll
        for (int m = 1; m < 64; m <<= 1) md = fmin(md, __shfl_xor(md, m));
        double zm = -md / BETA;
        double arg = (myk >= 0) ? (-myd / BETA - zm) : -1e300;
        double e = (myk >= 0) ? exp(arg) : 0.0;
        double esum = e;
        #pragma unroll
        for (int m = 1; m < 64; m <<= 1) esum += __shfl_xor(esum, m);

        unsigned long long smsk = __ballot(myk >= 0 && arg >= ACUT);
        while (smsk) {
            int l = __ffsll(smsk) - 1;
            smsk &= smsk - 1;
            double aw = __shfl(arg, l);
            int k = __shfl(myk, l);
            double wgt = exp(aw) / esum;
            atomicAdd(&num[(size_t)k * DIM + lane],      wgt * xa);
            atomicAdd(&num[(size_t)k * DIM + 64 + lane], wgt * xb);
            if (lane == 0) atomicAdd(&den[k], wgt);
        }
    }
}

// ---------------- k_update: centers = num/(den+EPS); refresh Cf64/Cfrag/csq; zero ----------------
__global__ void k_update(double* __restrict__ num, double* __restrict__ den,
                         double* __restrict__ Cf64, unsigned short* __restrict__ Cfrag,
                         double* __restrict__ csqd, float* __restrict__ csqf,
                         float* __restrict__ out, int last) {
    int k = blockIdx.x, d = threadIdx.x;       // 512 blocks x 128 threads
    double nv = num[(size_t)k * DIM + d];
    double dv = den[k] + EPS;
    double c = nv / dv;
    Cf64[(size_t)k * DIM + d] = c;
    num[(size_t)k * DIM + d] = 0.0;
    if (last) out[k * DIM + d] = (float)c;
    int ct = k >> 5, kb = d >> 4, j = d & 15;
    int lane = (k & 31) + 32 * (j >> 3);
    Cfrag[(((size_t)ct * 8 + kb) * 64 + lane) * 8 + (j & 7)] = f2bf((float)c);
    double p = c * c;
    #pragma unroll
    for (int m = 1; m < 64; m <<= 1) p += __shfl_xor(p, m);
    __shared__ double ps[2];
    if ((d & 63) == 0) ps[d >> 6] = p;
    __syncthreads();
    if (d == 0) { double s = ps[0] + ps[1]; csqd[k] = s; csqf[k] = (float)s; den[k] = 0.0; }
}

extern "C" void kernel_launch(void* const* d_in, const int* in_sizes, int n_in,
                              void* d_out, int out_size, void* d_ws, size_t ws_size,
                              hipStream_t stream) {
    const float* x   = (const float*)d_in[0];
    const float* cin = (const float*)d_in[1];
    float* out = (float*)d_out;

    char* w = (char*)d_ws;
    size_t off = 0;
    auto alloc = [&](size_t bytes) -> void* {
        void* p = w + off;
        off = (off + bytes + 255) & ~(size_t)255;
        return p;
    };
    double*         Cf64  = (double*)alloc((size_t)KC * DIM * 8);          // 512 KB
    unsigned short* Cfrag = (unsigned short*)alloc((size_t)KC * DIM * 2);  // 128 KB
    double*         csqd  = (double*)alloc((size_t)KC * 8);
    float*          csqf  = (float*)alloc((size_t)KC * 4);
    double*         num   = (double*)alloc((size_t)KC * DIM * 8);          // 512 KB
    double*         den   = (double*)alloc((size_t)KC * 8);
    short8*         Xf    = (short8*)alloc((size_t)N_PTS * DIM * 2);       // 51.2 MB
    (void)ws_size; (void)in_sizes; (void)n_in; (void)out_size;

    hipLaunchKernelGGL(k_init, dim3(KC), dim3(DIM), 0, stream,
                       cin, Cf64, Cfrag, csqd, csqf, num, den);
    hipLaunchKernelGGL(k_packx, dim3(N_PTS / 32), dim3(256), 0, stream, x, Xf);

    for (int it = 0; it < NITER; ++it) {
        hipLaunchKernelGGL(k_dense, dim3(N_PTS / 32), dim3(256), 0, stream,
                           x, Xf, (const short8*)Cfrag, csqf, Cf64, csqd, num, den);
        hipLaunchKernelGGL(k_update, dim3(KC), dim3(DIM), 0, stream,
                           num, den, Cf64, Cfrag, csqd, csqf, out,
                           (it == NITER - 1) ? 1 : 0);
    }
}

// Round 8
// 804.634 us; speedup vs baseline: 8.2399x; 1.0914x over previous
//
#include <hip/hip_runtime.h>

#define N_PTS 200000
#define KC    512
#define DIM   128
#define NITER 3
#define EPS   1e-10
#define BETA  1e-3
#define PWIN  0.35f     // bf16-pruner window: f64 arg>=-32 band (0.032) + >10sigma bf16 slack
#define ACUT  -32.0     // weights below e^-32 shift centers ~1e-12 -> negligible
#define LCAND 16
#define CAP   4096      // per-center entry bucket (expected ~395/center)

typedef __attribute__((ext_vector_type(8)))  short short8;   // 8 bf16 (4 VGPR) MFMA A/B frag
typedef __attribute__((ext_vector_type(16))) float f32x16;   // 32x32 MFMA accumulator

__device__ inline unsigned short f2bf(float f) {             // f32 -> bf16 RNE
    unsigned u = __float_as_uint(f);
    unsigned r = u + 0x7FFFu + ((u >> 16) & 1u);
    return (unsigned short)(r >> 16);
}

// A/B fragment layout for mfma_f32_32x32x16_bf16: entity row/col = lane&31,
// k = (lane>>5)*8 + i, i=0..7. Packed flat: [(tile*8 + kb)*64 + lane] as short8.

// ---------------- k_packx: X -> bf16 A-fragments (once; x is iteration-invariant) ----------------
__global__ void k_packx(const float* __restrict__ x, short8* __restrict__ Xf) {
    int pt = blockIdx.x;                       // 6250 point-tiles of 32
    int tid = threadIdx.x;                     // 256
    int lane = tid & 63, g = tid >> 6;
    int row = pt * 32 + (lane & 31);
    int koff = (lane >> 5) * 8;
    #pragma unroll
    for (int kk = 0; kk < 2; ++kk) {
        int kb = g * 2 + kk;
        short8 v;
        #pragma unroll
        for (int i = 0; i < 8; ++i)
            ((unsigned short*)&v)[i] = f2bf(x[(size_t)row * DIM + kb * 16 + koff + i]);
        Xf[((size_t)pt * 8 + kb) * 64 + lane] = v;
    }
}

// ---------------- k_init: Cf64, C-fragments, csq, zero num/den/cursor ----------------
__global__ void k_init(const float* __restrict__ cin, double* __restrict__ Cf64,
                       unsigned short* __restrict__ Cfrag, double* __restrict__ csqd,
                       float* __restrict__ csqf, double* __restrict__ num,
                       double* __restrict__ den, unsigned* __restrict__ cursor) {
    int k = blockIdx.x, d = threadIdx.x;       // 512 blocks x 128 threads
    float v = cin[k * DIM + d];
    double c = (double)v;
    Cf64[(size_t)k * DIM + d] = c;
    num[(size_t)k * DIM + d] = 0.0;
    int ct = k >> 5, kb = d >> 4, j = d & 15;
    int lane = (k & 31) + 32 * (j >> 3);
    Cfrag[(((size_t)ct * 8 + kb) * 64 + lane) * 8 + (j & 7)] = f2bf(v);
    double p = c * c;
    #pragma unroll
    for (int m = 1; m < 64; m <<= 1) p += __shfl_xor(p, m);
    __shared__ double ps[2];
    if ((d & 63) == 0) ps[d >> 6] = p;
    __syncthreads();
    if (d == 0) {
        double s = ps[0] + ps[1];
        csqd[k] = s; csqf[k] = (float)s;
        den[k] = 0.0; cursor[k] = 0u;
    }
}

// ---------------- k_dense: MFMA bf16 pruner + full-min + f64 refine + CSR append ----------------
// 256 threads = 4 waves; 32 points/block; wave wv covers col-tiles wv*4..wv*4+3 (128 centers).
__launch_bounds__(256)
__global__ void k_dense(const float* __restrict__ x, const short8* __restrict__ Xf,
                        const short8* __restrict__ Cfrag, const float* __restrict__ csqf,
                        const double* __restrict__ Cf64, const double* __restrict__ csqd,
                        unsigned* __restrict__ cursor,
                        unsigned* __restrict__ entries_n, double* __restrict__ entries_w) {
    __shared__ float rowmin_w[4][32];
    __shared__ float rowmin_s[32];
    __shared__ int   ccnt[32];
    __shared__ unsigned short clist[32][LCAND];

    const int tid = threadIdx.x;
    const int wv = tid >> 6, lane = tid & 63;
    const int blk = blockIdx.x;                // 6250 * 32 = 200000 exactly

    // A-fragments: this block's 32 points, full K=128 (32 VGPR)
    short8 a[8];
    #pragma unroll
    for (int kb = 0; kb < 8; ++kb)
        a[kb] = Xf[((size_t)blk * 8 + kb) * 64 + lane];

    // pruner: dd[t][r] = csq - 2*(x.c) in bf16/f32, held in registers
    float dd[4][16];
    #pragma unroll
    for (int t = 0; t < 4; ++t) {
        int ct = wv * 4 + t;
        f32x16 acc;
        #pragma unroll
        for (int r = 0; r < 16; ++r) acc[r] = 0.0f;
        #pragma unroll
        for (int kb = 0; kb < 8; ++kb) {
            short8 b = Cfrag[((size_t)ct * 8 + kb) * 64 + lane];
            acc = __builtin_amdgcn_mfma_f32_32x32x16_bf16(a[kb], b, acc, 0, 0, 0);
        }
        float cq = csqf[ct * 32 + (lane & 31)];
        #pragma unroll
        for (int r = 0; r < 16; ++r) dd[t][r] = cq - 2.0f * acc[r];
    }

    // per-row min over this wave's 128 cols (C/D layout: col=lane&31, row=(r&3)+8*(r>>2)+4*(lane>>5))
    float mt[16];
    #pragma unroll
    for (int r = 0; r < 16; ++r) {
        float m = fminf(fminf(dd[0][r], dd[1][r]), fminf(dd[2][r], dd[3][r]));
        #pragma unroll
        for (int s = 16; s >= 1; s >>= 1) m = fminf(m, __shfl_xor(m, s));
        mt[r] = m;
    }
    if ((lane & 31) == 0) {
        int h = lane >> 5;
        #pragma unroll
        for (int r = 0; r < 16; ++r)
            rowmin_w[wv][(r & 3) + 8 * (r >> 2) + 4 * h] = mt[r];
    }
    __syncthreads();
    if (tid < 32) {
        rowmin_s[tid] = fminf(fminf(rowmin_w[0][tid], rowmin_w[1][tid]),
                              fminf(rowmin_w[2][tid], rowmin_w[3][tid]));
        ccnt[tid] = 0;
    }
    __syncthreads();

    // candidate collection (full global min known BEFORE any collection)
    {
        const int h = lane >> 5;
        #pragma unroll
        for (int t = 0; t < 4; ++t) {
            int ct = wv * 4 + t;
            #pragma unroll
            for (int r = 0; r < 16; ++r) {
                int row = (r & 3) + 8 * (r >> 2) + 4 * h;
                if (dd[t][r] - rowmin_s[row] < PWIN) {
                    int idx = atomicAdd(&ccnt[row], 1);
                    if (idx < LCAND)
                        clist[row][idx] = (unsigned short)(ct * 32 + (lane & 31));
                }
            }
        }
    }
    __syncthreads();

    // exact f64 refine + softmax + CSR append; wave wv handles points wv*8..wv*8+7
    // ||x||^2 dropped: common mode in softmax (arg shift <= ~1e-10)
    for (int q = 0; q < 8; ++q) {
        int p = wv * 8 + q;
        int n = blk * 32 + p;
        int cnt = ccnt[p]; if (cnt > LCAND) cnt = LCAND;
        double xa = (double)x[(size_t)n * DIM + lane];
        double xb = (double)x[(size_t)n * DIM + 64 + lane];

        double myd = 1e300; int myk = -1;
        for (int c = 0; c < cnt; ++c) {
            int k = clist[p][c];
            double pr = xa * Cf64[(size_t)k * DIM + lane] + xb * Cf64[(size_t)k * DIM + 64 + lane];
            #pragma unroll
            for (int m = 1; m < 64; m <<= 1) pr += __shfl_xor(pr, m);
            double dist = csqd[k] - 2.0 * pr;
            if (lane == c) { myd = dist; myk = k; }
        }
        double md = myd;
        #pragma unroll
        for (int m = 1; m < 64; m <<= 1) md = fmin(md, __shfl_xor(md, m));
        double zm = -md / BETA;
        double arg = (myk >= 0) ? (-myd / BETA - zm) : -1e300;
        double e = (myk >= 0) ? exp(arg) : 0.0;
        double esum = e;
        #pragma unroll
        for (int m = 1; m < 64; m <<= 1) esum += __shfl_xor(esum, m);

        if (myk >= 0 && arg >= ACUT) {
            double wgt = e / esum;             // once, on the candidate lane only
            unsigned pos = atomicAdd(&cursor[myk], 1u);
            if (pos < CAP) {
                entries_n[(size_t)myk * CAP + pos] = (unsigned)n;
                entries_w[(size_t)myk * CAP + pos] = wgt;
            }
        }
    }
}

// ---------------- k_reduce: gather per-center entries, partial f64 sums ----------------
// 2048 blocks = 4 partials per center; 128 threads (one per dim)
__global__ void k_reduce(const float* __restrict__ x, const unsigned* __restrict__ cursor,
                         const unsigned* __restrict__ entries_n,
                         const double* __restrict__ entries_w,
                         double* __restrict__ num, double* __restrict__ den) {
    int b = blockIdx.x;
    int k = b >> 2, part = b & 3;
    int d = threadIdx.x;
    unsigned len = cursor[k]; if (len > CAP) len = CAP;
    unsigned beg = (part * len) >> 2, end = ((part + 1) * len) >> 2;
    const unsigned* en = entries_n + (size_t)k * CAP;
    const double*   ew = entries_w + (size_t)k * CAP;

    double a0 = 0.0, a1 = 0.0, a2 = 0.0, a3 = 0.0, ws = 0.0;
    unsigned e = beg;
    for (; e + 4 <= end; e += 4) {
        unsigned n0 = en[e], n1 = en[e + 1], n2 = en[e + 2], n3 = en[e + 3];
        double w0 = ew[e], w1 = ew[e + 1], w2 = ew[e + 2], w3 = ew[e + 3];
        float f0 = x[(size_t)n0 * DIM + d];
        float f1 = x[(size_t)n1 * DIM + d];
        float f2 = x[(size_t)n2 * DIM + d];
        float f3 = x[(size_t)n3 * DIM + d];
        a0 += w0 * (double)f0; a1 += w1 * (double)f1;
        a2 += w2 * (double)f2; a3 += w3 * (double)f3;
        ws += ((w0 + w1) + (w2 + w3));
    }
    for (; e < end; ++e) {
        unsigned n0 = en[e]; double w0 = ew[e];
        a0 += w0 * (double)x[(size_t)n0 * DIM + d];
        ws += w0;
    }
    double acc = (a0 + a1) + (a2 + a3);
    if (end > beg) {
        atomicAdd(&num[(size_t)k * DIM + d], acc);
        if (d == 0) atomicAdd(&den[k], ws);
    }
}

// ---------------- k_update: centers = num/(den+EPS); refresh; zero num/den/cursor ----------------
__global__ void k_update(double* __restrict__ num, double* __restrict__ den,
                         double* __restrict__ Cf64, unsigned short* __restrict__ Cfrag,
                         double* __restrict__ csqd, float* __restrict__ csqf,
                         unsigned* __restrict__ cursor, float* __restrict__ out, int last) {
    int k = blockIdx.x, d = threadIdx.x;       // 512 blocks x 128 threads
    double nv = num[(size_t)k * DIM + d];
    double dv = den[k] + EPS;
    double c = nv / dv;
    Cf64[(size_t)k * DIM + d] = c;
    num[(size_t)k * DIM + d] = 0.0;
    if (last) out[k * DIM + d] = (float)c;
    int ct = k >> 5, kb = d >> 4, j = d & 15;
    int lane = (k & 31) + 32 * (j >> 3);
    Cfrag[(((size_t)ct * 8 + kb) * 64 + lane) * 8 + (j & 7)] = f2bf((float)c);
    double p = c * c;
    #pragma unroll
    for (int m = 1; m < 64; m <<= 1) p += __shfl_xor(p, m);
    __shared__ double ps[2];
    if ((d & 63) == 0) ps[d >> 6] = p;
    __syncthreads();
    if (d == 0) {
        double s = ps[0] + ps[1];
        csqd[k] = s; csqf[k] = (float)s;
        den[k] = 0.0; cursor[k] = 0u;
    }
}

extern "C" void kernel_launch(void* const* d_in, const int* in_sizes, int n_in,
                              void* d_out, int out_size, void* d_ws, size_t ws_size,
                              hipStream_t stream) {
    const float* x   = (const float*)d_in[0];
    const float* cin = (const float*)d_in[1];
    float* out = (float*)d_out;

    char* w = (char*)d_ws;
    size_t off = 0;
    auto alloc = [&](size_t bytes) -> void* {
        void* p = w + off;
        off = (off + bytes + 255) & ~(size_t)255;
        return p;
    };
    double*         Cf64   = (double*)alloc((size_t)KC * DIM * 8);          // 512 KB
    unsigned short* Cfrag  = (unsigned short*)alloc((size_t)KC * DIM * 2);  // 128 KB
    double*         csqd   = (double*)alloc((size_t)KC * 8);
    float*          csqf   = (float*)alloc((size_t)KC * 4);
    double*         num    = (double*)alloc((size_t)KC * DIM * 8);          // 512 KB
    double*         den    = (double*)alloc((size_t)KC * 8);
    unsigned*       cursor = (unsigned*)alloc((size_t)KC * 4);
    unsigned*       entries_n = (unsigned*)alloc((size_t)KC * CAP * 4);     // 8.4 MB
    double*         entries_w = (double*)alloc((size_t)KC * CAP * 8);       // 16.8 MB
    short8*         Xf     = (short8*)alloc((size_t)N_PTS * DIM * 2);       // 51.2 MB
    (void)ws_size; (void)in_sizes; (void)n_in; (void)out_size;

    hipLaunchKernelGGL(k_init, dim3(KC), dim3(DIM), 0, stream,
                       cin, Cf64, Cfrag, csqd, csqf, num, den, cursor);
    hipLaunchKernelGGL(k_packx, dim3(N_PTS / 32), dim3(256), 0, stream, x, Xf);

    for (int it = 0; it < NITER; ++it) {
        hipLaunchKernelGGL(k_dense, dim3(N_PTS / 32), dim3(256), 0, stream,
                           x, Xf, (const short8*)Cfrag, csqf, Cf64, csqd,
                           cursor, entries_n, entries_w);
        hipLaunchKernelGGL(k_reduce, dim3(KC * 4), dim3(DIM), 0, stream,
                           x, cursor, entries_n, entries_w, num, den);
        hipLaunchKernelGGL(k_update, dim3(KC), dim3(DIM), 0, stream,
                           num, den, Cf64, Cfrag, csqd, csqf, cursor, out,
                           (it == NITER - 1) ? 1 : 0);
    }
}

// Round 9
// 682.075 us; speedup vs baseline: 9.7204x; 1.1797x over previous
//
#include <hip/hip_runtime.h>

#define N_PTS 200000
#define KC    512
#define DIM   128
#define NITER 3
#define EPS   1e-10
#define BETA  1e-3
#define PWIN  0.35f     // bf16-pruner window: f64 arg>=-32 band (0.032) + >10sigma bf16 slack
#define ACUT  -32.0     // weights below e^-32 shift centers ~1e-12 -> negligible
#define LCAND 16
#define CAP   4096      // per-center entry bucket (expected ~395/center)

typedef __attribute__((ext_vector_type(8)))  short short8;   // 8 bf16 (4 VGPR) MFMA A/B frag
typedef __attribute__((ext_vector_type(16))) float f32x16;   // 32x32 MFMA accumulator

__device__ inline unsigned short f2bf(float f) {             // f32 -> bf16 RNE
    unsigned u = __float_as_uint(f);
    unsigned r = u + 0x7FFFu + ((u >> 16) & 1u);
    return (unsigned short)(r >> 16);
}

// A/B fragment layout for mfma_f32_32x32x16_bf16: entity row/col = lane&31,
// k = (lane>>5)*8 + i, i=0..7. Packed flat: [(tile*8 + kb)*64 + lane] as short8.

// ---------------- k_packx: X -> bf16 A-fragments (once; x is iteration-invariant) ----------------
__global__ void k_packx(const float* __restrict__ x, short8* __restrict__ Xf) {
    int pt = blockIdx.x;                       // 6250 point-tiles of 32
    int tid = threadIdx.x;                     // 256
    int lane = tid & 63, g = tid >> 6;
    int row = pt * 32 + (lane & 31);
    int koff = (lane >> 5) * 8;
    #pragma unroll
    for (int kk = 0; kk < 2; ++kk) {
        int kb = g * 2 + kk;
        short8 v;
        #pragma unroll
        for (int i = 0; i < 8; ++i)
            ((unsigned short*)&v)[i] = f2bf(x[(size_t)row * DIM + kb * 16 + koff + i]);
        Xf[((size_t)pt * 8 + kb) * 64 + lane] = v;
    }
}

// ---------------- k_init: Cf64, C-fragments, csq, zero num/den/cursor ----------------
__global__ void k_init(const float* __restrict__ cin, double* __restrict__ Cf64,
                       unsigned short* __restrict__ Cfrag, double* __restrict__ csqd,
                       float* __restrict__ csqf, double* __restrict__ num,
                       double* __restrict__ den, unsigned* __restrict__ cursor) {
    int k = blockIdx.x, d = threadIdx.x;       // 512 blocks x 128 threads
    float v = cin[k * DIM + d];
    double c = (double)v;
    Cf64[(size_t)k * DIM + d] = c;
    num[(size_t)k * DIM + d] = 0.0;
    int ct = k >> 5, kb = d >> 4, j = d & 15;
    int lane = (k & 31) + 32 * (j >> 3);
    Cfrag[(((size_t)ct * 8 + kb) * 64 + lane) * 8 + (j & 7)] = f2bf(v);
    double p = c * c;
    #pragma unroll
    for (int m = 1; m < 64; m <<= 1) p += __shfl_xor(p, m);
    __shared__ double ps[2];
    if ((d & 63) == 0) ps[d >> 6] = p;
    __syncthreads();
    if (d == 0) {
        double s = ps[0] + ps[1];
        csqd[k] = s; csqf[k] = (float)s;
        den[k] = 0.0; cursor[k] = 0u;
    }
}

// ---------------- k_dense: MFMA bf16 pruner + full-min + f64 refine + CSR append ----------------
// 256 threads = 4 waves; 32 points/block; wave wv covers col-tiles wv*4..wv*4+3 (128 centers).
__launch_bounds__(256)
__global__ void k_dense(const float* __restrict__ x, const short8* __restrict__ Xf,
                        const short8* __restrict__ Cfrag, const float* __restrict__ csqf,
                        const double* __restrict__ Cf64, const double* __restrict__ csqd,
                        unsigned* __restrict__ cursor,
                        unsigned* __restrict__ entries_n, double* __restrict__ entries_w) {
    __shared__ float rowmin_w[4][32];
    __shared__ float rowmin_s[32];
    __shared__ int   ccnt[32];
    __shared__ unsigned short clist[32][LCAND];

    const int tid = threadIdx.x;
    const int wv = tid >> 6, lane = tid & 63;
    const int blk = blockIdx.x;                // 6250 * 32 = 200000 exactly

    // A-fragments: this block's 32 points, full K=128 (32 VGPR)
    short8 a[8];
    #pragma unroll
    for (int kb = 0; kb < 8; ++kb)
        a[kb] = Xf[((size_t)blk * 8 + kb) * 64 + lane];

    // pruner: dd[t][r] = csq - 2*(x.c) in bf16/f32, held in registers
    float dd[4][16];
    #pragma unroll
    for (int t = 0; t < 4; ++t) {
        int ct = wv * 4 + t;
        f32x16 acc;
        #pragma unroll
        for (int r = 0; r < 16; ++r) acc[r] = 0.0f;
        #pragma unroll
        for (int kb = 0; kb < 8; ++kb) {
            short8 b = Cfrag[((size_t)ct * 8 + kb) * 64 + lane];
            acc = __builtin_amdgcn_mfma_f32_32x32x16_bf16(a[kb], b, acc, 0, 0, 0);
        }
        float cq = csqf[ct * 32 + (lane & 31)];
        #pragma unroll
        for (int r = 0; r < 16; ++r) dd[t][r] = cq - 2.0f * acc[r];
    }

    // per-row min over this wave's 128 cols (C/D layout: col=lane&31, row=(r&3)+8*(r>>2)+4*(lane>>5))
    float mt[16];
    #pragma unroll
    for (int r = 0; r < 16; ++r) {
        float m = fminf(fminf(dd[0][r], dd[1][r]), fminf(dd[2][r], dd[3][r]));
        #pragma unroll
        for (int s = 16; s >= 1; s >>= 1) m = fminf(m, __shfl_xor(m, s));
        mt[r] = m;
    }
    if ((lane & 31) == 0) {
        int h = lane >> 5;
        #pragma unroll
        for (int r = 0; r < 16; ++r)
            rowmin_w[wv][(r & 3) + 8 * (r >> 2) + 4 * h] = mt[r];
    }
    __syncthreads();
    if (tid < 32) {
        rowmin_s[tid] = fminf(fminf(rowmin_w[0][tid], rowmin_w[1][tid]),
                              fminf(rowmin_w[2][tid], rowmin_w[3][tid]));
        ccnt[tid] = 0;
    }
    __syncthreads();

    // candidate collection (full global min known BEFORE any collection)
    {
        const int h = lane >> 5;
        #pragma unroll
        for (int t = 0; t < 4; ++t) {
            int ct = wv * 4 + t;
            #pragma unroll
            for (int r = 0; r < 16; ++r) {
                int row = (r & 3) + 8 * (r >> 2) + 4 * h;
                if (dd[t][r] - rowmin_s[row] < PWIN) {
                    int idx = atomicAdd(&ccnt[row], 1);
                    if (idx < LCAND)
                        clist[row][idx] = (unsigned short)(ct * 32 + (lane & 31));
                }
            }
        }
    }
    __syncthreads();

    // refine; wave wv handles points wv*8..wv*8+7.
    // cnt==1 fast path: sole candidate IS the argmin; all others sit >= ~e^-250 below
    // in f64 => weight is bit-exactly 1.0. No dot, no softmax, no x read.
    for (int q = 0; q < 8; ++q) {
        int p = wv * 8 + q;
        int n = blk * 32 + p;
        int cnt = ccnt[p]; if (cnt > LCAND) cnt = LCAND;

        if (cnt == 1) {
            if (lane == 0) {
                int k = clist[p][0];
                unsigned pos = atomicAdd(&cursor[k], 1u);
                if (pos < CAP) {
                    entries_n[(size_t)k * CAP + pos] = (unsigned)n;
                    entries_w[(size_t)k * CAP + pos] = 1.0;
                }
            }
            continue;
        }

        // exact f64 refine + softmax (||x||^2 dropped: common mode in softmax)
        double xa = (double)x[(size_t)n * DIM + lane];
        double xb = (double)x[(size_t)n * DIM + 64 + lane];

        double myd = 1e300; int myk = -1;
        for (int c = 0; c < cnt; ++c) {
            int k = clist[p][c];
            double pr = xa * Cf64[(size_t)k * DIM + lane] + xb * Cf64[(size_t)k * DIM + 64 + lane];
            #pragma unroll
            for (int m = 1; m < 64; m <<= 1) pr += __shfl_xor(pr, m);
            double dist = csqd[k] - 2.0 * pr;
            if (lane == c) { myd = dist; myk = k; }
        }
        double md = myd;
        #pragma unroll
        for (int m = 1; m < 64; m <<= 1) md = fmin(md, __shfl_xor(md, m));
        double zm = -md / BETA;
        double arg = (myk >= 0) ? (-myd / BETA - zm) : -1e300;
        double e = (myk >= 0) ? exp(arg) : 0.0;
        double esum = e;
        #pragma unroll
        for (int m = 1; m < 64; m <<= 1) esum += __shfl_xor(esum, m);

        if (myk >= 0 && arg >= ACUT) {
            double wgt = e / esum;             // once, on the candidate lane only
            unsigned pos = atomicAdd(&cursor[myk], 1u);
            if (pos < CAP) {
                entries_n[(size_t)myk * CAP + pos] = (unsigned)n;
                entries_w[(size_t)myk * CAP + pos] = wgt;
            }
        }
    }
}

// ---------------- k_reduce: gather per-center entries, partial f64 sums ----------------
// 2048 blocks = 4 partials per center; 128 threads (one per dim)
__global__ void k_reduce(const float* __restrict__ x, const unsigned* __restrict__ cursor,
                         const unsigned* __restrict__ entries_n,
                         const double* __restrict__ entries_w,
                         double* __restrict__ num, double* __restrict__ den) {
    int b = blockIdx.x;
    int k = b >> 2, part = b & 3;
    int d = threadIdx.x;
    unsigned len = cursor[k]; if (len > CAP) len = CAP;
    unsigned beg = (part * len) >> 2, end = ((part + 1) * len) >> 2;
    const unsigned* en = entries_n + (size_t)k * CAP;
    const double*   ew = entries_w + (size_t)k * CAP;

    double a0 = 0.0, a1 = 0.0, a2 = 0.0, a3 = 0.0, ws = 0.0;
    unsigned e = beg;
    for (; e + 4 <= end; e += 4) {
        unsigned n0 = en[e], n1 = en[e + 1], n2 = en[e + 2], n3 = en[e + 3];
        double w0 = ew[e], w1 = ew[e + 1], w2 = ew[e + 2], w3 = ew[e + 3];
        float f0 = x[(size_t)n0 * DIM + d];
        float f1 = x[(size_t)n1 * DIM + d];
        float f2 = x[(size_t)n2 * DIM + d];
        float f3 = x[(size_t)n3 * DIM + d];
        a0 += w0 * (double)f0; a1 += w1 * (double)f1;
        a2 += w2 * (double)f2; a3 += w3 * (double)f3;
        ws += ((w0 + w1) + (w2 + w3));
    }
    for (; e < end; ++e) {
        unsigned n0 = en[e]; double w0 = ew[e];
        a0 += w0 * (double)x[(size_t)n0 * DIM + d];
        ws += w0;
    }
    double acc = (a0 + a1) + (a2 + a3);
    if (end > beg) {
        atomicAdd(&num[(size_t)k * DIM + d], acc);
        if (d == 0) atomicAdd(&den[k], ws);
    }
}

// ---------------- k_update: centers = num/(den+EPS); refresh; zero num/den/cursor ----------------
__global__ void k_update(double* __restrict__ num, double* __restrict__ den,
                         double* __restrict__ Cf64, unsigned short* __restrict__ Cfrag,
                         double* __restrict__ csqd, float* __restrict__ csqf,
                         unsigned* __restrict__ cursor, float* __restrict__ out, int last) {
    int k = blockIdx.x, d = threadIdx.x;       // 512 blocks x 128 threads
    double nv = num[(size_t)k * DIM + d];
    double dv = den[k] + EPS;
    double c = nv / dv;
    Cf64[(size_t)k * DIM + d] = c;
    num[(size_t)k * DIM + d] = 0.0;
    if (last) out[k * DIM + d] = (float)c;
    int ct = k >> 5, kb = d >> 4, j = d & 15;
    int lane = (k & 31) + 32 * (j >> 3);
    Cfrag[(((size_t)ct * 8 + kb) * 64 + lane) * 8 + (j & 7)] = f2bf((float)c);
    double p = c * c;
    #pragma unroll
    for (int m = 1; m < 64; m <<= 1) p += __shfl_xor(p, m);
    __shared__ double ps[2];
    if ((d & 63) == 0) ps[d >> 6] = p;
    __syncthreads();
    if (d == 0) {
        double s = ps[0] + ps[1];
        csqd[k] = s; csqf[k] = (float)s;
        den[k] = 0.0; cursor[k] = 0u;
    }
}

extern "C" void kernel_launch(void* const* d_in, const int* in_sizes, int n_in,
                              void* d_out, int out_size, void* d_ws, size_t ws_size,
                              hipStream_t stream) {
    const float* x   = (const float*)d_in[0];
    const float* cin = (const float*)d_in[1];
    float* out = (float*)d_out;

    char* w = (char*)d_ws;
    size_t off = 0;
    auto alloc = [&](size_t bytes) -> void* {
        void* p = w + off;
        off = (off + bytes + 255) & ~(size_t)255;
        return p;
    };
    double*         Cf64   = (double*)alloc((size_t)KC * DIM * 8);          // 512 KB
    unsigned short* Cfrag  = (unsigned short*)alloc((size_t)KC * DIM * 2);  // 128 KB
    double*         csqd   = (double*)alloc((size_t)KC * 8);
    float*          csqf   = (float*)alloc((size_t)KC * 4);
    double*         num    = (double*)alloc((size_t)KC * DIM * 8);          // 512 KB
    double*         den    = (double*)alloc((size_t)KC * 8);
    unsigned*       cursor = (unsigned*)alloc((size_t)KC * 4);
    unsigned*       entries_n = (unsigned*)alloc((size_t)KC * CAP * 4);     // 8.4 MB
    double*         entries_w = (double*)alloc((size_t)KC * CAP * 8);       // 16.8 MB
    short8*         Xf     = (short8*)alloc((size_t)N_PTS * DIM * 2);       // 51.2 MB
    (void)ws_size; (void)in_sizes; (void)n_in; (void)out_size;

    hipLaunchKernelGGL(k_init, dim3(KC), dim3(DIM), 0, stream,
                       cin, Cf64, Cfrag, csqd, csqf, num, den, cursor);
    hipLaunchKernelGGL(k_packx, dim3(N_PTS / 32), dim3(256), 0, stream, x, Xf);

    for (int it = 0; it < NITER; ++it) {
        hipLaunchKernelGGL(k_dense, dim3(N_PTS / 32), dim3(256), 0, stream,
                           x, Xf, (const short8*)Cfrag, csqf, Cf64, csqd,
                           cursor, entries_n, entries_w);
        hipLaunchKernelGGL(k_reduce, dim3(KC * 4), dim3(DIM), 0, stream,
                           x, cursor, entries_n, entries_w, num, den);
        hipLaunchKernelGGL(k_update, dim3(KC), dim3(DIM), 0, stream,
                           num, den, Cf64, Cfrag, csqd, csqf, cursor, out,
                           (it == NITER - 1) ? 1 : 0);
    }
}

// Round 10
// 645.098 us; speedup vs baseline: 10.2776x; 1.0573x over previous
//
#include <hip/hip_runtime.h>

#define N_PTS 200000
#define KC    512
#define DIM   128
#define NITER 3
#define EPS   1e-10
#define BETA  1e-3
#define PWIN  0.35f     // bf16-pruner window: f64 arg>=-32 band (0.032) + >10sigma bf16 slack
#define ACUT  -32.0     // weights below e^-32 shift centers ~1e-12 -> negligible
#define LCAND 16
#define CAP   4096      // per-center entry bucket (expected ~395/center)

typedef __attribute__((ext_vector_type(8)))  short short8;   // 8 bf16 (4 VGPR) MFMA A/B frag
typedef __attribute__((ext_vector_type(16))) float f32x16;   // 32x32 MFMA accumulator

__device__ inline unsigned short f2bf(float f) {             // f32 -> bf16 RNE
    unsigned u = __float_as_uint(f);
    unsigned r = u + 0x7FFFu + ((u >> 16) & 1u);
    return (unsigned short)(r >> 16);
}

// A/B fragment layout for mfma_f32_32x32x16_bf16: entity row/col = lane&31,
// k = (lane>>5)*8 + i, i=0..7. Packed flat: [(tile*8 + kb)*64 + lane] as short8.

// ---------------- k_packx: X -> bf16 A-fragments (once; x is iteration-invariant) ----------------
__global__ void k_packx(const float* __restrict__ x, short8* __restrict__ Xf) {
    int pt = blockIdx.x;                       // 6250 point-tiles of 32
    int tid = threadIdx.x;                     // 256
    int lane = tid & 63, g = tid >> 6;
    int row = pt * 32 + (lane & 31);
    int koff = (lane >> 5) * 8;
    #pragma unroll
    for (int kk = 0; kk < 2; ++kk) {
        int kb = g * 2 + kk;
        short8 v;
        #pragma unroll
        for (int i = 0; i < 8; ++i)
            ((unsigned short*)&v)[i] = f2bf(x[(size_t)row * DIM + kb * 16 + koff + i]);
        Xf[((size_t)pt * 8 + kb) * 64 + lane] = v;
    }
}

// ---------------- k_init: Cf64, C-fragments, csq, zero num/den/cursor ----------------
__global__ void k_init(const float* __restrict__ cin, double* __restrict__ Cf64,
                       unsigned short* __restrict__ Cfrag, double* __restrict__ csqd,
                       float* __restrict__ csqf, double* __restrict__ num,
                       double* __restrict__ den, unsigned* __restrict__ cursor) {
    int k = blockIdx.x, d = threadIdx.x;       // 512 blocks x 128 threads
    float v = cin[k * DIM + d];
    double c = (double)v;
    Cf64[(size_t)k * DIM + d] = c;
    num[(size_t)k * DIM + d] = 0.0;
    int ct = k >> 5, kb = d >> 4, j = d & 15;
    int lane = (k & 31) + 32 * (j >> 3);
    Cfrag[(((size_t)ct * 8 + kb) * 64 + lane) * 8 + (j & 7)] = f2bf(v);
    double p = c * c;
    #pragma unroll
    for (int m = 1; m < 64; m <<= 1) p += __shfl_xor(p, m);
    __shared__ double ps[2];
    if ((d & 63) == 0) ps[d >> 6] = p;
    __syncthreads();
    if (d == 0) {
        double s = ps[0] + ps[1];
        csqd[k] = s; csqf[k] = (float)s;
        den[k] = 0.0; cursor[k] = 0u;
    }
}

// ---------------- k_dense: MFMA bf16 pruner + full-min + f64 refine + CSR append ----------------
// 256 threads = 4 waves; 32 points/block; wave wv covers col-tiles wv*4..wv*4+3 (128 centers).
__launch_bounds__(256)
__global__ void k_dense(const float* __restrict__ x, const short8* __restrict__ Xf,
                        const short8* __restrict__ Cfrag, const float* __restrict__ csqf,
                        const double* __restrict__ Cf64, const double* __restrict__ csqd,
                        unsigned* __restrict__ cursor,
                        unsigned* __restrict__ entries_n, double* __restrict__ entries_w) {
    __shared__ float rowmin_w[4][32];
    __shared__ float rowmin_s[32];
    __shared__ int   ccnt[32];
    __shared__ unsigned short clist[32][LCAND];
    __shared__ int   wl[32];
    __shared__ int   wlcnt;

    const int tid = threadIdx.x;
    const int wv = tid >> 6, lane = tid & 63;
    const int blk = blockIdx.x;                // 6250 * 32 = 200000 exactly

    // A-fragments: this block's 32 points, full K=128 (32 VGPR)
    short8 a[8];
    #pragma unroll
    for (int kb = 0; kb < 8; ++kb)
        a[kb] = Xf[((size_t)blk * 8 + kb) * 64 + lane];

    // pruner: dd[t][r] = csq - 2*(x.c) in bf16/f32, held in registers
    float dd[4][16];
    #pragma unroll
    for (int t = 0; t < 4; ++t) {
        int ct = wv * 4 + t;
        f32x16 acc;
        #pragma unroll
        for (int r = 0; r < 16; ++r) acc[r] = 0.0f;
        #pragma unroll
        for (int kb = 0; kb < 8; ++kb) {
            short8 b = Cfrag[((size_t)ct * 8 + kb) * 64 + lane];
            acc = __builtin_amdgcn_mfma_f32_32x32x16_bf16(a[kb], b, acc, 0, 0, 0);
        }
        float cq = csqf[ct * 32 + (lane & 31)];
        #pragma unroll
        for (int r = 0; r < 16; ++r) dd[t][r] = cq - 2.0f * acc[r];
    }

    // per-row min over this wave's 128 cols (C/D layout: col=lane&31, row=(r&3)+8*(r>>2)+4*(lane>>5))
    float mt[16];
    #pragma unroll
    for (int r = 0; r < 16; ++r) {
        float m = fminf(fminf(dd[0][r], dd[1][r]), fminf(dd[2][r], dd[3][r]));
        #pragma unroll
        for (int s = 16; s >= 1; s >>= 1) m = fminf(m, __shfl_xor(m, s));
        mt[r] = m;
    }
    if ((lane & 31) == 0) {
        int h = lane >> 5;
        #pragma unroll
        for (int r = 0; r < 16; ++r)
            rowmin_w[wv][(r & 3) + 8 * (r >> 2) + 4 * h] = mt[r];
    }
    __syncthreads();
    if (tid < 32) {
        rowmin_s[tid] = fminf(fminf(rowmin_w[0][tid], rowmin_w[1][tid]),
                              fminf(rowmin_w[2][tid], rowmin_w[3][tid]));
        ccnt[tid] = 0;
    }
    if (tid == 0) wlcnt = 0;
    __syncthreads();

    // candidate collection (full global min known BEFORE any collection)
    {
        const int h = lane >> 5;
        #pragma unroll
        for (int t = 0; t < 4; ++t) {
            int ct = wv * 4 + t;
            #pragma unroll
            for (int r = 0; r < 16; ++r) {
                int row = (r & 3) + 8 * (r >> 2) + 4 * h;
                if (dd[t][r] - rowmin_s[row] < PWIN) {
                    int idx = atomicAdd(&ccnt[row], 1);
                    if (idx < LCAND)
                        clist[row][idx] = (unsigned short)(ct * 32 + (lane & 31));
                }
            }
        }
    }
    __syncthreads();

    // cnt==1 fast path, PARALLEL: lanes 0..7 of wave wv handle its 8 points at once.
    // Sole candidate IS the argmin; all others sit >= ~e^-250 below in f64
    // => weight is bit-exactly 1.0. No dot, no softmax, no x read.
    {
        int p = wv * 8 + (lane & 7);
        if (lane < 8 && ccnt[p] == 1) {
            int k = clist[p][0];
            unsigned pos = atomicAdd(&cursor[k], 1u);
            if (pos < CAP) {
                entries_n[(size_t)k * CAP + pos] = (unsigned)(blk * 32 + p);
                entries_w[(size_t)k * CAP + pos] = 1.0;
            }
        }
    }
    // worklist of cnt>=2 points; all 4 waves strip-mine it (load balance)
    if (tid < 32 && ccnt[tid] > 1) {
        int i = atomicAdd(&wlcnt, 1);
        wl[i] = tid;
    }
    __syncthreads();

    int nwl = wlcnt;
    for (int i = wv; i < nwl; i += 4) {
        int p = wl[i];
        int n = blk * 32 + p;
        int cnt = ccnt[p]; if (cnt > LCAND) cnt = LCAND;

        // exact f64 refine + softmax (||x||^2 dropped: common mode in softmax)
        double xa = (double)x[(size_t)n * DIM + lane];
        double xb = (double)x[(size_t)n * DIM + 64 + lane];

        double myd = 1e300; int myk = -1;
        for (int c = 0; c < cnt; ++c) {
            int k = clist[p][c];
            double pr = xa * Cf64[(size_t)k * DIM + lane] + xb * Cf64[(size_t)k * DIM + 64 + lane];
            #pragma unroll
            for (int m = 1; m < 64; m <<= 1) pr += __shfl_xor(pr, m);
            double dist = csqd[k] - 2.0 * pr;
            if (lane == c) { myd = dist; myk = k; }
        }
        double md = myd;
        #pragma unroll
        for (int m = 1; m < 64; m <<= 1) md = fmin(md, __shfl_xor(md, m));
        double zm = -md / BETA;
        double arg = (myk >= 0) ? (-myd / BETA - zm) : -1e300;
        double e = (myk >= 0) ? exp(arg) : 0.0;
        double esum = e;
        #pragma unroll
        for (int m = 1; m < 64; m <<= 1) esum += __shfl_xor(esum, m);

        if (myk >= 0 && arg >= ACUT) {
            double wgt = e / esum;             // once, on the candidate lane only
            unsigned pos = atomicAdd(&cursor[myk], 1u);
            if (pos < CAP) {
                entries_n[(size_t)myk * CAP + pos] = (unsigned)n;
                entries_w[(size_t)myk * CAP + pos] = wgt;
            }
        }
    }
}

// ---------------- k_reduce: gather per-center entries, partial f64 sums ----------------
// 2048 blocks = 4 partials per center; 128 threads (one per dim)
__global__ void k_reduce(const float* __restrict__ x, const unsigned* __restrict__ cursor,
                         const unsigned* __restrict__ entries_n,
                         const double* __restrict__ entries_w,
                         double* __restrict__ num, double* __restrict__ den) {
    int b = blockIdx.x;
    int k = b >> 2, part = b & 3;
    int d = threadIdx.x;
    unsigned len = cursor[k]; if (len > CAP) len = CAP;
    unsigned beg = (part * len) >> 2, end = ((part + 1) * len) >> 2;
    const unsigned* en = entries_n + (size_t)k * CAP;
    const double*   ew = entries_w + (size_t)k * CAP;

    double a0 = 0.0, a1 = 0.0, a2 = 0.0, a3 = 0.0, ws = 0.0;
    unsigned e = beg;
    for (; e + 4 <= end; e += 4) {
        unsigned n0 = en[e], n1 = en[e + 1], n2 = en[e + 2], n3 = en[e + 3];
        double w0 = ew[e], w1 = ew[e + 1], w2 = ew[e + 2], w3 = ew[e + 3];
        float f0 = x[(size_t)n0 * DIM + d];
        float f1 = x[(size_t)n1 * DIM + d];
        float f2 = x[(size_t)n2 * DIM + d];
        float f3 = x[(size_t)n3 * DIM + d];
        a0 += w0 * (double)f0; a1 += w1 * (double)f1;
        a2 += w2 * (double)f2; a3 += w3 * (double)f3;
        ws += ((w0 + w1) + (w2 + w3));
    }
    for (; e < end; ++e) {
        unsigned n0 = en[e]; double w0 = ew[e];
        a0 += w0 * (double)x[(size_t)n0 * DIM + d];
        ws += w0;
    }
    double acc = (a0 + a1) + (a2 + a3);
    if (end > beg) {
        atomicAdd(&num[(size_t)k * DIM + d], acc);
        if (d == 0) atomicAdd(&den[k], ws);
    }
}

// ---------------- k_update: centers = num/(den+EPS); refresh; zero num/den/cursor ----------------
__global__ void k_update(double* __restrict__ num, double* __restrict__ den,
                         double* __restrict__ Cf64, unsigned short* __restrict__ Cfrag,
                         double* __restrict__ csqd, float* __restrict__ csqf,
                         unsigned* __restrict__ cursor, float* __restrict__ out, int last) {
    int k = blockIdx.x, d = threadIdx.x;       // 512 blocks x 128 threads
    double nv = num[(size_t)k * DIM + d];
    double dv = den[k] + EPS;
    double c = nv / dv;
    Cf64[(size_t)k * DIM + d] = c;
    num[(size_t)k * DIM + d] = 0.0;
    if (last) out[k * DIM + d] = (float)c;
    int ct = k >> 5, kb = d >> 4, j = d & 15;
    int lane = (k & 31) + 32 * (j >> 3);
    Cfrag[(((size_t)ct * 8 + kb) * 64 + lane) * 8 + (j & 7)] = f2bf((float)c);
    double p = c * c;
    #pragma unroll
    for (int m = 1; m < 64; m <<= 1) p += __shfl_xor(p, m);
    __shared__ double ps[2];
    if ((d & 63) == 0) ps[d >> 6] = p;
    __syncthreads();
    if (d == 0) {
        double s = ps[0] + ps[1];
        csqd[k] = s; csqf[k] = (float)s;
        den[k] = 0.0; cursor[k] = 0u;
    }
}

extern "C" void kernel_launch(void* const* d_in, const int* in_sizes, int n_in,
                              void* d_out, int out_size, void* d_ws, size_t ws_size,
                              hipStream_t stream) {
    const float* x   = (const float*)d_in[0];
    const float* cin = (const float*)d_in[1];
    float* out = (float*)d_out;

    char* w = (char*)d_ws;
    size_t off = 0;
    auto alloc = [&](size_t bytes) -> void* {
        void* p = w + off;
        off = (off + bytes + 255) & ~(size_t)255;
        return p;
    };
    double*         Cf64   = (double*)alloc((size_t)KC * DIM * 8);          // 512 KB
    unsigned short* Cfrag  = (unsigned short*)alloc((size_t)KC * DIM * 2);  // 128 KB
    double*         csqd   = (double*)alloc((size_t)KC * 8);
    float*          csqf   = (float*)alloc((size_t)KC * 4);
    double*         num    = (double*)alloc((size_t)KC * DIM * 8);          // 512 KB
    double*         den    = (double*)alloc((size_t)KC * 8);
    unsigned*       cursor = (unsigned*)alloc((size_t)KC * 4);
    unsigned*       entries_n = (unsigned*)alloc((size_t)KC * CAP * 4);     // 8.4 MB
    double*         entries_w = (double*)alloc((size_t)KC * CAP * 8);       // 16.8 MB
    short8*         Xf     = (short8*)alloc((size_t)N_PTS * DIM * 2);       // 51.2 MB
    (void)ws_size; (void)in_sizes; (void)n_in; (void)out_size;

    hipLaunchKernelGGL(k_init, dim3(KC), dim3(DIM), 0, stream,
                       cin, Cf64, Cfrag, csqd, csqf, num, den, cursor);
    hipLaunchKernelGGL(k_packx, dim3(N_PTS / 32), dim3(256), 0, stream, x, Xf);

    for (int it = 0; it < NITER; ++it) {
        hipLaunchKernelGGL(k_dense, dim3(N_PTS / 32), dim3(256), 0, stream,
                           x, Xf, (const short8*)Cfrag, csqf, Cf64, csqd,
                           cursor, entries_n, entries_w);
        hipLaunchKernelGGL(k_reduce, dim3(KC * 4), dim3(DIM), 0, stream,
                           x, cursor, entries_n, entries_w, num, den);
        hipLaunchKernelGGL(k_update, dim3(KC), dim3(DIM), 0, stream,
                           num, den, Cf64, Cfrag, csqd, csqf, cursor, out,
                           (it == NITER - 1) ? 1 : 0);
    }
}

// Round 11
// 500.423 us; speedup vs baseline: 13.2489x; 1.2891x over previous
//
#include <hip/hip_runtime.h>

#define N_PTS 200000
#define KC    512
#define DIM   128
#define NITER 3
#define EPS   1e-10
#define BETA  1e-3
#define PWIN  0.35f     // bf16-pruner window: f64 arg>=-32 band (0.032) + >10sigma bf16 slack
#define ACUT  -32.0     // weights below e^-32 shift centers ~1e-12 -> negligible
#define LCAND 16
#define NSUB  8         // sub-buckets per center (atomic line-contention fix)
#define SUBCAP 512      // per-sub bucket capacity (total 4096/center, as R10)
#define CSTRIDE 16      // cursor padded to 64 B: one cache line per sub-cursor

typedef __attribute__((ext_vector_type(8)))  short short8;   // 8 bf16 (4 VGPR) MFMA A/B frag
typedef __attribute__((ext_vector_type(16))) float f32x16;   // 32x32 MFMA accumulator

__device__ inline unsigned short f2bf(float f) {             // f32 -> bf16 RNE
    unsigned u = __float_as_uint(f);
    unsigned r = u + 0x7FFFu + ((u >> 16) & 1u);
    return (unsigned short)(r >> 16);
}

// A/B fragment layout for mfma_f32_32x32x16_bf16: entity row/col = lane&31,
// k = (lane>>5)*8 + i, i=0..7. Packed flat: [(tile*8 + kb)*64 + lane] as short8.

// ---------------- k_packx: X -> bf16 A-fragments (once; x is iteration-invariant) ----------------
__global__ void k_packx(const float* __restrict__ x, short8* __restrict__ Xf) {
    int pt = blockIdx.x;                       // 6250 point-tiles of 32
    int tid = threadIdx.x;                     // 256
    int lane = tid & 63, g = tid >> 6;
    int row = pt * 32 + (lane & 31);
    int koff = (lane >> 5) * 8;
    #pragma unroll
    for (int kk = 0; kk < 2; ++kk) {
        int kb = g * 2 + kk;
        short8 v;
        #pragma unroll
        for (int i = 0; i < 8; ++i)
            ((unsigned short*)&v)[i] = f2bf(x[(size_t)row * DIM + kb * 16 + koff + i]);
        Xf[((size_t)pt * 8 + kb) * 64 + lane] = v;
    }
}

// ---------------- k_init: Cf64, C-fragments, csq, zero num/den/cursors ----------------
__global__ void k_init(const float* __restrict__ cin, double* __restrict__ Cf64,
                       unsigned short* __restrict__ Cfrag, double* __restrict__ csqd,
                       float* __restrict__ csqf, double* __restrict__ num,
                       double* __restrict__ den, unsigned* __restrict__ cursor) {
    int k = blockIdx.x, d = threadIdx.x;       // 512 blocks x 128 threads
    float v = cin[k * DIM + d];
    double c = (double)v;
    Cf64[(size_t)k * DIM + d] = c;
    num[(size_t)k * DIM + d] = 0.0;
    if (d < NSUB) cursor[((size_t)k * NSUB + d) * CSTRIDE] = 0u;
    int ct = k >> 5, kb = d >> 4, j = d & 15;
    int lane = (k & 31) + 32 * (j >> 3);
    Cfrag[(((size_t)ct * 8 + kb) * 64 + lane) * 8 + (j & 7)] = f2bf(v);
    double p = c * c;
    #pragma unroll
    for (int m = 1; m < 64; m <<= 1) p += __shfl_xor(p, m);
    __shared__ double ps[2];
    if ((d & 63) == 0) ps[d >> 6] = p;
    __syncthreads();
    if (d == 0) {
        double s = ps[0] + ps[1];
        csqd[k] = s; csqf[k] = (float)s;
        den[k] = 0.0;
    }
}

// ---------------- k_dense: MFMA bf16 pruner + full-min + f64 refine + CSR append ----------------
// 256 threads = 4 waves; 32 points/block; wave wv covers col-tiles wv*4..wv*4+3 (128 centers).
__launch_bounds__(256)
__global__ void k_dense(const float* __restrict__ x, const short8* __restrict__ Xf,
                        const short8* __restrict__ Cfrag, const float* __restrict__ csqf,
                        const double* __restrict__ Cf64, const double* __restrict__ csqd,
                        unsigned* __restrict__ cursor,
                        unsigned* __restrict__ entries_n, double* __restrict__ entries_w) {
    __shared__ float rowmin_w[4][32];
    __shared__ float rowmin_s[32];
    __shared__ int   ccnt[32];
    __shared__ unsigned short clist[32][LCAND];
    __shared__ int   wl[32];
    __shared__ int   wlcnt;

    const int tid = threadIdx.x;
    const int wv = tid >> 6, lane = tid & 63;
    const int blk = blockIdx.x;                // 6250 * 32 = 200000 exactly
    const int sub = blk & (NSUB - 1);

    // A-fragments: this block's 32 points, full K=128 (32 VGPR)
    short8 a[8];
    #pragma unroll
    for (int kb = 0; kb < 8; ++kb)
        a[kb] = Xf[((size_t)blk * 8 + kb) * 64 + lane];

    // pruner: dd[t][r] = csq - 2*(x.c) in bf16/f32, held in registers
    float dd[4][16];
    #pragma unroll
    for (int t = 0; t < 4; ++t) {
        int ct = wv * 4 + t;
        f32x16 acc;
        #pragma unroll
        for (int r = 0; r < 16; ++r) acc[r] = 0.0f;
        #pragma unroll
        for (int kb = 0; kb < 8; ++kb) {
            short8 b = Cfrag[((size_t)ct * 8 + kb) * 64 + lane];
            acc = __builtin_amdgcn_mfma_f32_32x32x16_bf16(a[kb], b, acc, 0, 0, 0);
        }
        float cq = csqf[ct * 32 + (lane & 31)];
        #pragma unroll
        for (int r = 0; r < 16; ++r) dd[t][r] = cq - 2.0f * acc[r];
    }

    // per-row min over this wave's 128 cols (C/D layout: col=lane&31, row=(r&3)+8*(r>>2)+4*(lane>>5))
    float mt[16];
    #pragma unroll
    for (int r = 0; r < 16; ++r) {
        float m = fminf(fminf(dd[0][r], dd[1][r]), fminf(dd[2][r], dd[3][r]));
        #pragma unroll
        for (int s = 16; s >= 1; s >>= 1) m = fminf(m, __shfl_xor(m, s));
        mt[r] = m;
    }
    if ((lane & 31) == 0) {
        int h = lane >> 5;
        #pragma unroll
        for (int r = 0; r < 16; ++r)
            rowmin_w[wv][(r & 3) + 8 * (r >> 2) + 4 * h] = mt[r];
    }
    __syncthreads();
    if (tid < 32) {
        rowmin_s[tid] = fminf(fminf(rowmin_w[0][tid], rowmin_w[1][tid]),
                              fminf(rowmin_w[2][tid], rowmin_w[3][tid]));
        ccnt[tid] = 0;
    }
    if (tid == 0) wlcnt = 0;
    __syncthreads();

    // candidate collection (full global min known BEFORE any collection)
    {
        const int h = lane >> 5;
        #pragma unroll
        for (int t = 0; t < 4; ++t) {
            int ct = wv * 4 + t;
            #pragma unroll
            for (int r = 0; r < 16; ++r) {
                int row = (r & 3) + 8 * (r >> 2) + 4 * h;
                if (dd[t][r] - rowmin_s[row] < PWIN) {
                    int idx = atomicAdd(&ccnt[row], 1);
                    if (idx < LCAND)
                        clist[row][idx] = (unsigned short)(ct * 32 + (lane & 31));
                }
            }
        }
    }
    __syncthreads();

    // cnt==1 fast path, PARALLEL: lanes 0..7 of wave wv handle its 8 points at once.
    // Sole candidate IS the argmin; all others sit >= ~e^-250 below in f64
    // => weight is bit-exactly 1.0. No dot, no softmax, no x read.
    {
        int p = wv * 8 + (lane & 7);
        if (lane < 8 && ccnt[p] == 1) {
            int k = clist[p][0];
            size_t base = (size_t)k * NSUB + sub;
            unsigned pos = atomicAdd(&cursor[base * CSTRIDE], 1u);
            if (pos < SUBCAP) {
                entries_n[base * SUBCAP + pos] = (unsigned)(blk * 32 + p);
                entries_w[base * SUBCAP + pos] = 1.0;
            }
        }
    }
    // worklist of cnt>=2 points; all 4 waves strip-mine it (load balance)
    if (tid < 32 && ccnt[tid] > 1) {
        int i = atomicAdd(&wlcnt, 1);
        wl[i] = tid;
    }
    __syncthreads();

    int nwl = wlcnt;
    for (int i = wv; i < nwl; i += 4) {
        int p = wl[i];
        int n = blk * 32 + p;
        int cnt = ccnt[p]; if (cnt > LCAND) cnt = LCAND;

        // exact f64 refine + softmax (||x||^2 dropped: common mode in softmax)
        double xa = (double)x[(size_t)n * DIM + lane];
        double xb = (double)x[(size_t)n * DIM + 64 + lane];

        double myd = 1e300; int myk = -1;
        for (int c = 0; c < cnt; ++c) {
            int k = clist[p][c];
            double pr = xa * Cf64[(size_t)k * DIM + lane] + xb * Cf64[(size_t)k * DIM + 64 + lane];
            #pragma unroll
            for (int m = 1; m < 64; m <<= 1) pr += __shfl_xor(pr, m);
            double dist = csqd[k] - 2.0 * pr;
            if (lane == c) { myd = dist; myk = k; }
        }
        double md = myd;
        #pragma unroll
        for (int m = 1; m < 64; m <<= 1) md = fmin(md, __shfl_xor(md, m));
        double zm = -md / BETA;
        double arg = (myk >= 0) ? (-myd / BETA - zm) : -1e300;
        double e = (myk >= 0) ? exp(arg) : 0.0;
        double esum = e;
        #pragma unroll
        for (int m = 1; m < 64; m <<= 1) esum += __shfl_xor(esum, m);

        if (myk >= 0 && arg >= ACUT) {
            double wgt = e / esum;             // once, on the candidate lane only
            size_t base = (size_t)myk * NSUB + sub;
            unsigned pos = atomicAdd(&cursor[base * CSTRIDE], 1u);
            if (pos < SUBCAP) {
                entries_n[base * SUBCAP + pos] = (unsigned)n;
                entries_w[base * SUBCAP + pos] = wgt;
            }
        }
    }
}

// ---------------- k_reduce: gather per-center entries, partial f64 sums ----------------
// 2048 blocks = 4 partials per center (2 sub-buckets each); 128 threads (one per dim)
__global__ void k_reduce(const float* __restrict__ x, const unsigned* __restrict__ cursor,
                         const unsigned* __restrict__ entries_n,
                         const double* __restrict__ entries_w,
                         double* __restrict__ num, double* __restrict__ den) {
    int b = blockIdx.x;
    int k = b >> 2, part = b & 3;
    int d = threadIdx.x;

    double a0 = 0.0, a1 = 0.0, a2 = 0.0, a3 = 0.0, ws = 0.0;
    #pragma unroll
    for (int s = 0; s < 2; ++s) {
        int sub = part * 2 + s;
        size_t base = (size_t)k * NSUB + sub;
        unsigned len = cursor[base * CSTRIDE]; if (len > SUBCAP) len = SUBCAP;
        const unsigned* en = entries_n + base * SUBCAP;
        const double*   ew = entries_w + base * SUBCAP;
        unsigned e = 0;
        for (; e + 4 <= len; e += 4) {
            unsigned n0 = en[e], n1 = en[e + 1], n2 = en[e + 2], n3 = en[e + 3];
            double w0 = ew[e], w1 = ew[e + 1], w2 = ew[e + 2], w3 = ew[e + 3];
            float f0 = x[(size_t)n0 * DIM + d];
            float f1 = x[(size_t)n1 * DIM + d];
            float f2 = x[(size_t)n2 * DIM + d];
            float f3 = x[(size_t)n3 * DIM + d];
            a0 += w0 * (double)f0; a1 += w1 * (double)f1;
            a2 += w2 * (double)f2; a3 += w3 * (double)f3;
            ws += ((w0 + w1) + (w2 + w3));
        }
        for (; e < len; ++e) {
            unsigned n0 = en[e]; double w0 = ew[e];
            a0 += w0 * (double)x[(size_t)n0 * DIM + d];
            ws += w0;
        }
    }
    double acc = (a0 + a1) + (a2 + a3);
    atomicAdd(&num[(size_t)k * DIM + d], acc);
    if (d == 0) atomicAdd(&den[k], ws);
}

// ---------------- k_update: centers = num/(den+EPS); refresh; zero num/den/cursors ----------------
__global__ void k_update(double* __restrict__ num, double* __restrict__ den,
                         double* __restrict__ Cf64, unsigned short* __restrict__ Cfrag,
                         double* __restrict__ csqd, float* __restrict__ csqf,
                         unsigned* __restrict__ cursor, float* __restrict__ out, int last) {
    int k = blockIdx.x, d = threadIdx.x;       // 512 blocks x 128 threads
    double nv = num[(size_t)k * DIM + d];
    double dv = den[k] + EPS;
    double c = nv / dv;
    Cf64[(size_t)k * DIM + d] = c;
    num[(size_t)k * DIM + d] = 0.0;
    if (d < NSUB) cursor[((size_t)k * NSUB + d) * CSTRIDE] = 0u;
    if (last) out[k * DIM + d] = (float)c;
    int ct = k >> 5, kb = d >> 4, j = d & 15;
    int lane = (k & 31) + 32 * (j >> 3);
    Cfrag[(((size_t)ct * 8 + kb) * 64 + lane) * 8 + (j & 7)] = f2bf((float)c);
    double p = c * c;
    #pragma unroll
    for (int m = 1; m < 64; m <<= 1) p += __shfl_xor(p, m);
    __shared__ double ps[2];
    if ((d & 63) == 0) ps[d >> 6] = p;
    __syncthreads();
    if (d == 0) {
        double s = ps[0] + ps[1];
        csqd[k] = s; csqf[k] = (float)s;
        den[k] = 0.0;
    }
}

extern "C" void kernel_launch(void* const* d_in, const int* in_sizes, int n_in,
                              void* d_out, int out_size, void* d_ws, size_t ws_size,
                              hipStream_t stream) {
    const float* x   = (const float*)d_in[0];
    const float* cin = (const float*)d_in[1];
    float* out = (float*)d_out;

    char* w = (char*)d_ws;
    size_t off = 0;
    auto alloc = [&](size_t bytes) -> void* {
        void* p = w + off;
        off = (off + bytes + 255) & ~(size_t)255;
        return p;
    };
    double*         Cf64   = (double*)alloc((size_t)KC * DIM * 8);          // 512 KB
    unsigned short* Cfrag  = (unsigned short*)alloc((size_t)KC * DIM * 2);  // 128 KB
    double*         csqd   = (double*)alloc((size_t)KC * 8);
    float*          csqf   = (float*)alloc((size_t)KC * 4);
    double*         num    = (double*)alloc((size_t)KC * DIM * 8);          // 512 KB
    double*         den    = (double*)alloc((size_t)KC * 8);
    unsigned*       cursor = (unsigned*)alloc((size_t)KC * NSUB * CSTRIDE * 4);   // 256 KB
    unsigned*       entries_n = (unsigned*)alloc((size_t)KC * NSUB * SUBCAP * 4); // 8.4 MB
    double*         entries_w = (double*)alloc((size_t)KC * NSUB * SUBCAP * 8);   // 16.8 MB
    short8*         Xf     = (short8*)alloc((size_t)N_PTS * DIM * 2);       // 51.2 MB
    (void)ws_size; (void)in_sizes; (void)n_in; (void)out_size;

    hipLaunchKernelGGL(k_init, dim3(KC), dim3(DIM), 0, stream,
                       cin, Cf64, Cfrag, csqd, csqf, num, den, cursor);
    hipLaunchKernelGGL(k_packx, dim3(N_PTS / 32), dim3(256), 0, stream, x, Xf);

    for (int it = 0; it < NITER; ++it) {
        hipLaunchKernelGGL(k_dense, dim3(N_PTS / 32), dim3(256), 0, stream,
                           x, Xf, (const short8*)Cfrag, csqf, Cf64, csqd,
                           cursor, entries_n, entries_w);
        hipLaunchKernelGGL(k_reduce, dim3(KC * 4), dim3(DIM), 0, stream,
                           x, cursor, entries_n, entries_w, num, den);
        hipLaunchKernelGGL(k_update, dim3(KC), dim3(DIM), 0, stream,
                           num, den, Cf64, Cfrag, csqd, csqf, cursor, out,
                           (it == NITER - 1) ? 1 : 0);
    }
}